// Round 8
// baseline (334.347 us; speedup 1.0000x reference)
//
#include <hip/hip_runtime.h>
#include <math.h>

// ---------------------------------------------------------------------------
// GAT x2 + linear + log_softmax on MI355X. R19.
//   - R18 post-mortem: gat_agg gather is memory-pattern-bound (~2.1 TB/s
//     beyond-L2 random 128B gathers) — instruction tweaks dead. R18's
//     adaptive chunks + gemm hoists regressed; reverted to R17 forms.
//   - R19: fuse the dense layers into the agg epilogues.
//     * agg_gemm2: block = 64 nodes (4 waves x 16 serial, R17 gather body),
//       rows -> LDS (b1+relu, bf16), barrier, then gemm_mfma2 body verbatim
//       reading A-fragments from LDS. Writes hbf2 + as2/ad2.
//       Kills gemm_mfma2 kernel + habg 12.8MB write + 12.8MB read.
//     * agg_final: same structure; rows (+b2) -> LDS, then final_lsm body
//       from LDS -> out. Kills final_lsm kernel + 25.6MB round-trip.
//     * Pipeline 6 kernels -> 4. LDS 27/23 KB -> 6-7 blocks/CU.
//   - fused_hist_gemm / bucket_fill unchanged (R15/R17 proven).
// ---------------------------------------------------------------------------

#define NEG_SLOPE 0.2f
#define NEG_BIG -3.0e38f

#define BSHIFT 9
#define BSIZE 512            // nodes per bucket
#define CEPB 8192            // edges per chunk block
#define ECAP 112             // ebuf records per (bucket,chunk) slot
#define CBPAD 256            // blockHist row stride

typedef __bf16 bf16x8 __attribute__((ext_vector_type(8)));
typedef __bf16 bf16x4 __attribute__((ext_vector_type(4)));
typedef float f32x4 __attribute__((ext_vector_type(4)));

__device__ __forceinline__ float lrelu(float x) {
    return x >= 0.f ? x : NEG_SLOPE * x;
}

__device__ __forceinline__ int wave_incl_scan(int v, int lane) {
#pragma unroll
    for (int d = 1; d < 64; d <<= 1) {
        int t = __shfl_up(v, d, 64);
        if (lane >= d) v += t;
    }
    return v;
}

// ---------------- fused: hist+place || gemm1 (K=128, fp32 A hi/lo) ---------

__global__ __launch_bounds__(256) void fused_hist_gemm(
        const int* __restrict__ src, const int* __restrict__ dst,
        int* __restrict__ bucketCount, int* __restrict__ blockHist,
        unsigned* __restrict__ ebuf, int E, int CB,
        const float* __restrict__ X, const float* __restrict__ W,
        const float* __restrict__ a_src, const float* __restrict__ a_dst,
        __bf16* __restrict__ Hout, float* __restrict__ as_, float* __restrict__ ad_,
        int N, int nTiles) {
    constexpr int K = 128;
    __shared__ __bf16 Whi[64][K + 8];
    __shared__ __bf16 Wlo[64][K + 8];
    __shared__ int hist[256];

    if (blockIdx.x < (unsigned)CB) {
        // ---- hist+place path: LDS rank capture, direct slotted ebuf write --
        const int t = threadIdx.x;
        hist[t] = 0;
        __syncthreads();
        const int c = blockIdx.x;
        const int e0 = c * CEPB;
        const int e1 = min(e0 + CEPB, E);
        int rr[CEPB / 256];
#pragma unroll
        for (int i = 0; i < CEPB / 256; ++i) {
            int e = e0 + i * 256 + t;
            if (e < e1) rr[i] = atomicAdd(&hist[dst[e] >> BSHIFT], 1);
        }
        __syncthreads();
        int hv = hist[t];
        blockHist[t * CBPAD + c] = hv;                    // plain store
        if (hv > 0) atomicAdd(&bucketCount[t], hv);       // fire-and-forget
#pragma unroll
        for (int i = 0; i < CEPB / 256; ++i) {
            int e = e0 + i * 256 + t;
            if (e < e1) {
                int d = dst[e];                            // L1/L2 hot
                int b = d >> BSHIFT;
                ebuf[((size_t)b * CB + c) * ECAP + rr[i]] =
                    ((unsigned)src[e] << BSHIFT) | (unsigned)(d & (BSIZE - 1));
            }
        }
        return;
    }

    // ---- gemm path ----
    const int gbid = blockIdx.x - CB;
    for (int idx = threadIdx.x; idx < K * 64; idx += 256) {
        int k = idx >> 6, n = idx & 63;
        float w = W[idx];
        __bf16 hi = (__bf16)w;
        Whi[n][k] = hi;
        Wlo[n][k] = (__bf16)(w - (float)hi);
    }
    __syncthreads();

    const int lane  = threadIdx.x & 63;
    const int wave  = threadIdx.x >> 6;
    const int row16 = lane & 15;
    const int quad  = lane >> 4;

    float asv[4], adv[4];
#pragma unroll
    for (int t = 0; t < 4; ++t) {
        asv[t] = a_src[t * 16 + row16];
        adv[t] = a_dst[t * 16 + row16];
    }

    for (int tile = gbid; tile < nTiles; tile += 1024) {
        const int nbase = tile * 64;
        int gn = nbase + wave * 16 + row16;
        if (gn >= N) gn = N - 1;
        const float* __restrict__ xp = X + (size_t)gn * K + quad * 8;

        float4 xv[K / 16];
#pragma unroll
        for (int c = 0; c < K / 32; ++c) {
            xv[2 * c]     = *(const float4*)(xp + c * 32);
            xv[2 * c + 1] = *(const float4*)(xp + c * 32 + 4);
        }

        f32x4 acc[4] = {{0.f, 0.f, 0.f, 0.f}, {0.f, 0.f, 0.f, 0.f},
                        {0.f, 0.f, 0.f, 0.f}, {0.f, 0.f, 0.f, 0.f}};
#pragma unroll
        for (int kc = 0; kc < K; kc += 32) {
            float xs[8];
            *(float4*)&xs[0] = xv[kc / 16];
            *(float4*)&xs[4] = xv[kc / 16 + 1];
            bf16x8 ahi, alo;
#pragma unroll
            for (int j = 0; j < 8; ++j) {
                __bf16 hi = (__bf16)xs[j];
                ahi[j] = hi;
                alo[j] = (__bf16)(xs[j] - (float)hi);
            }
#pragma unroll
            for (int t = 0; t < 4; ++t) {
                bf16x8 bhi = *(const bf16x8*)&Whi[t * 16 + row16][kc + quad * 8];
                bf16x8 blo = *(const bf16x8*)&Wlo[t * 16 + row16][kc + quad * 8];
                acc[t] = __builtin_amdgcn_mfma_f32_16x16x32_bf16(ahi, bhi, acc[t], 0, 0, 0);
                acc[t] = __builtin_amdgcn_mfma_f32_16x16x32_bf16(ahi, blo, acc[t], 0, 0, 0);
                acc[t] = __builtin_amdgcn_mfma_f32_16x16x32_bf16(alo, bhi, acc[t], 0, 0, 0);
            }
        }

        float ps[4] = {0.f, 0.f, 0.f, 0.f};
        float pd[4] = {0.f, 0.f, 0.f, 0.f};
#pragma unroll
        for (int t = 0; t < 4; ++t) {
#pragma unroll
            for (int r = 0; r < 4; ++r) {
                int gm = nbase + wave * 16 + quad * 4 + r;
                if (gm < N) Hout[(size_t)gm * 64 + t * 16 + row16] = (__bf16)acc[t][r];
                ps[r] = fmaf(acc[t][r], asv[t], ps[r]);
                pd[r] = fmaf(acc[t][r], adv[t], pd[r]);
            }
        }
#pragma unroll
        for (int r = 0; r < 4; ++r) {
#pragma unroll
            for (int d = 1; d < 16; d <<= 1) {
                ps[r] += __shfl_xor(ps[r], d, 64);
                pd[r] += __shfl_xor(pd[r], d, 64);
            }
        }
        if (row16 == 0) {
#pragma unroll
            for (int r = 0; r < 4; ++r) {
                int gm = nbase + wave * 16 + quad * 4 + r;
                if (gm < N) { as_[gm] = ps[r]; ad_[gm] = pd[r]; }
            }
        }
    }
}

// ---------------- per-bucket: gbase + offs + csr fill (LDS ranks) ----------

__global__ __launch_bounds__(1024) void bucket_fill(const unsigned* __restrict__ ebuf,
                                                    const int* __restrict__ blockHist,
                                                    const int* __restrict__ bucketCount,
                                                    int* __restrict__ offs,
                                                    int* __restrict__ csr,
                                                    int N, int E, int CB) {
    __shared__ int hist[512], excls[512], bhist_s[256], wsum[16], gsum[16];
    const int b = blockIdx.x;
    const int t = threadIdx.x;       // 0..1023
    const int lane = t & 63;
    const int w = t >> 6;            // 0..15

    // gbase = sum of bucketCount[0..b-1] (waves 0..3 carry data)
    int v = (t < 256 && t < b) ? bucketCount[t] : 0;
#pragma unroll
    for (int d = 32; d; d >>= 1) v += __shfl_xor(v, d, 64);
    if (lane == 0) gsum[w] = v;
    if (t < 512) hist[t] = 0;
    if (t < 256) bhist_s[t] = blockHist[b * CBPAD + t];
    if (b == 0 && t == 0) offs[N] = E;
    __syncthreads();
    int gbase = 0;
#pragma unroll
    for (int i = 0; i < 16; ++i) gbase += gsum[i];

    // phase 1: node-degree histogram with register rank capture.
    int rr[32];
#pragma unroll
    for (int ci = 0; ci < 16; ++ci) {
        int c = w + ci * 16;
        int cnt = (c < CB) ? bhist_s[c] : 0;
        const unsigned* __restrict__ ep = ebuf + ((size_t)b * CB + c) * ECAP;
#pragma unroll
        for (int ri = 0; ri < 2; ++ri) {
            int idx = ri * 64 + lane;
            if (idx < cnt) {
                unsigned rec = ep[idx];
                rr[ci * 2 + ri] = atomicAdd(&hist[rec & (BSIZE - 1)], 1);
            }
        }
    }
    __syncthreads();

    // phase 2: 512-entry exclusive scan (waves 0..7) -> offs
    int hv = (t < 512) ? hist[t] : 0;
    int incl = wave_incl_scan(hv, lane);
    if (lane == 63 && w < 8) wsum[w] = incl;
    __syncthreads();
    if (t < 512) {
        int pre = 0;
#pragma unroll
        for (int i = 0; i < 8; ++i) pre += (i < w) ? wsum[i] : 0;
        int excl = incl - hv + pre;
        int n = b * BSIZE + t;
        if (n < N) offs[n] = gbase + excl;
        excls[t] = excl;
    }
    __syncthreads();

    // phase 3: write csr (re-read ebuf region, L2-hot)
#pragma unroll
    for (int ci = 0; ci < 16; ++ci) {
        int c = w + ci * 16;
        int cnt = (c < CB) ? bhist_s[c] : 0;
        const unsigned* __restrict__ ep = ebuf + ((size_t)b * CB + c) * ECAP;
#pragma unroll
        for (int ri = 0; ri < 2; ++ri) {
            int idx = ri * 64 + lane;
            if (idx < cnt) {
                unsigned rec = ep[idx];
                csr[gbase + excls[rec & (BSIZE - 1)] + rr[ci * 2 + ri]] =
                    (int)(rec >> BSHIFT);
            }
        }
    }
}

// ---- agg layer-1 (R17 gather, rows->LDS) + gemm2 MFMA from LDS ------------

__global__ __launch_bounds__(256) void agg_gemm2(
        const __bf16* __restrict__ h, const float* __restrict__ as_,
        const float* __restrict__ ad_, const float* __restrict__ bias,
        const int* __restrict__ offs, const int* __restrict__ csr,
        const float* __restrict__ W, const float* __restrict__ a_src2,
        const float* __restrict__ a_dst2, __bf16* __restrict__ Hout,
        float* __restrict__ as2, float* __restrict__ ad2, int N) {
    __shared__ __bf16 Whi[64][72];
    __shared__ __bf16 Wlo[64][72];
    __shared__ __bf16 rows[64][68];

    // stage W2 hi/lo (no barrier needed until MFMA phase)
    for (int idx = threadIdx.x; idx < 64 * 64; idx += 256) {
        int k = idx >> 6, n = idx & 63;
        float w = W[idx];
        __bf16 hi = (__bf16)w;
        Whi[n][k] = hi;
        Wlo[n][k] = (__bf16)(w - (float)hi);
    }

    const int lane = threadIdx.x & 63;
    const int wave = threadIdx.x >> 6;
    const int g  = lane >> 4;   // edge group 0..3
    const int fl = lane & 15;   // feature quad index
    const int nbase = blockIdx.x * 64;
    const float4 b4 = *(const float4*)(bias + fl * 4);

    // ---- gather phase: wave handles 16 nodes (slots wave*16 .. +15) ----
    for (int i = 0; i < 16; ++i) {
        const int slot = wave * 16 + i;
        const int n = nbase + slot;
        if (n >= N) {
            if (g == 0) {
                bf16x4 z;
                z[0] = (__bf16)0.f; z[1] = (__bf16)0.f;
                z[2] = (__bf16)0.f; z[3] = (__bf16)0.f;
                *(bf16x4*)&rows[slot][fl * 4] = z;
            }
            continue;
        }
        int beg = offs[n], end = offs[n + 1];
        float adn = ad_[n];
        float p_self = __expf(lrelu(as_[n] + adn));

        float den = p_self;
        float ax, ay, az, aw;
        {
            bf16x4 t = *(const bf16x4*)(h + (size_t)n * 64 + fl * 4);
            float m0 = (g == 0) ? p_self : 0.f;
            ax = m0 * (float)t[0];
            ay = m0 * (float)t[1];
            az = m0 * (float)t[2];
            aw = m0 * (float)t[3];
        }

        for (int c0 = beg; c0 < end; c0 += 64) {
            int cnt = end - c0;
            if (cnt > 64) cnt = 64;
            int   s_l = (lane < cnt) ? csr[c0 + lane] : 0;
            float p_l = (lane < cnt) ? __expf(lrelu(as_[s_l] + adn)) : 0.f;
            float csum = p_l;
#pragma unroll
            for (int d = 32; d; d >>= 1) csum += __shfl_xor(csum, d, 64);
            den += csum;

            // 8 independent gathers in flight per iteration (32 edges).
            int rounds = (cnt + 3) >> 2;
            for (int r = 0; r < rounds; r += 8) {
                int s[8];
#pragma unroll
                for (int j = 0; j < 8; ++j) s[j] = __shfl(s_l, (r + j) * 4 + g, 64);
                bf16x4 hv[8];
#pragma unroll
                for (int j = 0; j < 8; ++j)
                    hv[j] = *(const bf16x4*)(h + (size_t)s[j] * 64 + fl * 4);
                float w8[8];
#pragma unroll
                for (int j = 0; j < 8; ++j) w8[j] = __shfl(p_l, (r + j) * 4 + g, 64);
#pragma unroll
                for (int j = 0; j < 8; ++j) {
                    ax = fmaf(w8[j], (float)hv[j][0], ax);
                    ay = fmaf(w8[j], (float)hv[j][1], ay);
                    az = fmaf(w8[j], (float)hv[j][2], az);
                    aw = fmaf(w8[j], (float)hv[j][3], aw);
                }
            }
        }

#pragma unroll
        for (int d = 16; d <= 32; d <<= 1) {
            ax += __shfl_xor(ax, d, 64);
            ay += __shfl_xor(ay, d, 64);
            az += __shfl_xor(az, d, 64);
            aw += __shfl_xor(aw, d, 64);
        }
        if (g == 0) {
            float inv = 1.f / (den + 1e-16f);
            bf16x4 ov;
            ov[0] = (__bf16)fmaxf(fmaf(ax, inv, b4.x), 0.f);
            ov[1] = (__bf16)fmaxf(fmaf(ay, inv, b4.y), 0.f);
            ov[2] = (__bf16)fmaxf(fmaf(az, inv, b4.z), 0.f);
            ov[3] = (__bf16)fmaxf(fmaf(aw, inv, b4.w), 0.f);
            *(bf16x4*)&rows[slot][fl * 4] = ov;
        }
    }
    __syncthreads();

    // ---- gemm2 phase (gemm_mfma2 body, A from LDS rows) ----
    const int row16 = lane & 15;
    const int quad  = lane >> 4;

    float asv[4], adv[4];
#pragma unroll
    for (int t = 0; t < 4; ++t) {
        asv[t] = a_src2[t * 16 + row16];
        adv[t] = a_dst2[t * 16 + row16];
    }

    const __bf16* xp = &rows[wave * 16 + row16][quad * 8];
    bf16x8 a0 = *(const bf16x8*)(xp);
    bf16x8 a1 = *(const bf16x8*)(xp + 32);

    f32x4 acc[4] = {{0.f, 0.f, 0.f, 0.f}, {0.f, 0.f, 0.f, 0.f},
                    {0.f, 0.f, 0.f, 0.f}, {0.f, 0.f, 0.f, 0.f}};
#pragma unroll
    for (int kc = 0; kc < 64; kc += 32) {
        bf16x8 a = (kc == 0) ? a0 : a1;
#pragma unroll
        for (int t = 0; t < 4; ++t) {
            bf16x8 bhi = *(const bf16x8*)&Whi[t * 16 + row16][kc + quad * 8];
            bf16x8 blo = *(const bf16x8*)&Wlo[t * 16 + row16][kc + quad * 8];
            acc[t] = __builtin_amdgcn_mfma_f32_16x16x32_bf16(a, bhi, acc[t], 0, 0, 0);
            acc[t] = __builtin_amdgcn_mfma_f32_16x16x32_bf16(a, blo, acc[t], 0, 0, 0);
        }
    }

    float ps[4] = {0.f, 0.f, 0.f, 0.f};
    float pd[4] = {0.f, 0.f, 0.f, 0.f};
#pragma unroll
    for (int t = 0; t < 4; ++t) {
#pragma unroll
        for (int r = 0; r < 4; ++r) {
            int gm = nbase + wave * 16 + quad * 4 + r;
            if (gm < N) Hout[(size_t)gm * 64 + t * 16 + row16] = (__bf16)acc[t][r];
            ps[r] = fmaf(acc[t][r], asv[t], ps[r]);
            pd[r] = fmaf(acc[t][r], adv[t], pd[r]);
        }
    }
#pragma unroll
    for (int r = 0; r < 4; ++r) {
#pragma unroll
        for (int d = 1; d < 16; d <<= 1) {
            ps[r] += __shfl_xor(ps[r], d, 64);
            pd[r] += __shfl_xor(pd[r], d, 64);
        }
    }
    if (row16 == 0) {
#pragma unroll
        for (int r = 0; r < 4; ++r) {
            int gm = nbase + wave * 16 + quad * 4 + r;
            if (gm < N) { as2[gm] = ps[r]; ad2[gm] = pd[r]; }
        }
    }
}

// ---- agg layer-2 (R17 gather, rows->LDS) + final linear+lsm from LDS ------

__global__ __launch_bounds__(256) void agg_final(
        const __bf16* __restrict__ h, const float* __restrict__ as_,
        const float* __restrict__ ad_, const float* __restrict__ bias,
        const int* __restrict__ offs, const int* __restrict__ csr,
        const float* __restrict__ Wl, const float* __restrict__ bl,
        float* __restrict__ out, int N) {
    __shared__ __bf16 Whi[48][72];
    __shared__ __bf16 Wlo[48][72];
    __shared__ float bls[48];
    __shared__ __bf16 rows[64][68];

    for (int idx = threadIdx.x; idx < 48 * 64; idx += 256) {
        int c = idx >> 6, k = idx & 63;
        float w = (c < 40) ? Wl[k * 40 + c] : 0.f;
        __bf16 hi = (__bf16)w;
        Whi[c][k] = hi;
        Wlo[c][k] = (__bf16)(w - (float)hi);
    }
    if (threadIdx.x < 48) bls[threadIdx.x] = (threadIdx.x < 40) ? bl[threadIdx.x] : 0.f;

    const int lane = threadIdx.x & 63;
    const int wave = threadIdx.x >> 6;
    const int g  = lane >> 4;
    const int fl = lane & 15;
    const int nbase = blockIdx.x * 64;
    const float4 b4 = *(const float4*)(bias + fl * 4);

    for (int i = 0; i < 16; ++i) {
        const int slot = wave * 16 + i;
        const int n = nbase + slot;
        if (n >= N) {
            if (g == 0) {
                bf16x4 z;
                z[0] = (__bf16)0.f; z[1] = (__bf16)0.f;
                z[2] = (__bf16)0.f; z[3] = (__bf16)0.f;
                *(bf16x4*)&rows[slot][fl * 4] = z;
            }
            continue;
        }
        int beg = offs[n], end = offs[n + 1];
        float adn = ad_[n];
        float p_self = __expf(lrelu(as_[n] + adn));

        float den = p_self;
        float ax, ay, az, aw;
        {
            bf16x4 t = *(const bf16x4*)(h + (size_t)n * 64 + fl * 4);
            float m0 = (g == 0) ? p_self : 0.f;
            ax = m0 * (float)t[0];
            ay = m0 * (float)t[1];
            az = m0 * (float)t[2];
            aw = m0 * (float)t[3];
        }

        for (int c0 = beg; c0 < end; c0 += 64) {
            int cnt = end - c0;
            if (cnt > 64) cnt = 64;
            int   s_l = (lane < cnt) ? csr[c0 + lane] : 0;
            float p_l = (lane < cnt) ? __expf(lrelu(as_[s_l] + adn)) : 0.f;
            float csum = p_l;
#pragma unroll
            for (int d = 32; d; d >>= 1) csum += __shfl_xor(csum, d, 64);
            den += csum;

            int rounds = (cnt + 3) >> 2;
            for (int r = 0; r < rounds; r += 8) {
                int s[8];
#pragma unroll
                for (int j = 0; j < 8; ++j) s[j] = __shfl(s_l, (r + j) * 4 + g, 64);
                bf16x4 hv[8];
#pragma unroll
                for (int j = 0; j < 8; ++j)
                    hv[j] = *(const bf16x4*)(h + (size_t)s[j] * 64 + fl * 4);
                float w8[8];
#pragma unroll
                for (int j = 0; j < 8; ++j) w8[j] = __shfl(p_l, (r + j) * 4 + g, 64);
#pragma unroll
                for (int j = 0; j < 8; ++j) {
                    ax = fmaf(w8[j], (float)hv[j][0], ax);
                    ay = fmaf(w8[j], (float)hv[j][1], ay);
                    az = fmaf(w8[j], (float)hv[j][2], az);
                    aw = fmaf(w8[j], (float)hv[j][3], aw);
                }
            }
        }

#pragma unroll
        for (int d = 16; d <= 32; d <<= 1) {
            ax += __shfl_xor(ax, d, 64);
            ay += __shfl_xor(ay, d, 64);
            az += __shfl_xor(az, d, 64);
            aw += __shfl_xor(aw, d, 64);
        }
        if (g == 0) {
            float inv = 1.f / (den + 1e-16f);
            bf16x4 ov;
            ov[0] = (__bf16)fmaf(ax, inv, b4.x);
            ov[1] = (__bf16)fmaf(ay, inv, b4.y);
            ov[2] = (__bf16)fmaf(az, inv, b4.z);
            ov[3] = (__bf16)fmaf(aw, inv, b4.w);
            *(bf16x4*)&rows[slot][fl * 4] = ov;
        }
    }
    __syncthreads();

    // ---- final linear + log_softmax (final_lsm body, A from LDS rows) ----
    const int col16 = lane & 15;
    const int quad  = lane >> 4;

    const __bf16* xp = &rows[wave * 16 + col16][quad * 8];
    bf16x8 a0 = *(const bf16x8*)(xp);
    bf16x8 a1 = *(const bf16x8*)(xp + 32);

    f32x4 acc[3] = {{0.f, 0.f, 0.f, 0.f}, {0.f, 0.f, 0.f, 0.f},
                    {0.f, 0.f, 0.f, 0.f}};
#pragma unroll
    for (int kc = 0; kc < 64; kc += 32) {
        bf16x8 a = (kc == 0) ? a0 : a1;
#pragma unroll
        for (int t = 0; t < 3; ++t) {
            bf16x8 bhi = *(const bf16x8*)&Whi[t * 16 + col16][kc + quad * 8];
            bf16x8 blo = *(const bf16x8*)&Wlo[t * 16 + col16][kc + quad * 8];
            acc[t] = __builtin_amdgcn_mfma_f32_16x16x32_bf16(a, bhi, acc[t], 0, 0, 0);
            acc[t] = __builtin_amdgcn_mfma_f32_16x16x32_bf16(a, blo, acc[t], 0, 0, 0);
        }
    }

#pragma unroll
    for (int r = 0; r < 4; ++r) {
        int gm = nbase + wave * 16 + quad * 4 + r;
        float l0 = acc[0][r] + bls[col16];
        float l1 = acc[1][r] + bls[16 + col16];
        float l2 = (col16 < 8) ? (acc[2][r] + bls[32 + col16]) : NEG_BIG;
        float mx = fmaxf(fmaxf(l0, l1), l2);
#pragma unroll
        for (int d = 1; d < 16; d <<= 1) mx = fmaxf(mx, __shfl_xor(mx, d, 64));
        float s = __expf(l0 - mx) + __expf(l1 - mx) +
                  ((col16 < 8) ? __expf(l2 - mx) : 0.f);
#pragma unroll
        for (int d = 1; d < 16; d <<= 1) s += __shfl_xor(s, d, 64);
        float lse = mx + __logf(s);
        if (gm < N) {
            out[(size_t)gm * 40 + col16]      = l0 - lse;
            out[(size_t)gm * 40 + 16 + col16] = l1 - lse;
            if (col16 < 8) out[(size_t)gm * 40 + 32 + col16] = l2 - lse;
        }
    }
}

// ---------------- launch ----------------

extern "C" void kernel_launch(void* const* d_in, const int* in_sizes, int n_in,
                              void* d_out, int out_size, void* d_ws, size_t ws_size,
                              hipStream_t stream) {
    const float* x      = (const float*)d_in[0];
    const int*   ei     = (const int*)d_in[1];
    const float* W1     = (const float*)d_in[2];
    const float* a_src1 = (const float*)d_in[3];
    const float* a_dst1 = (const float*)d_in[4];
    const float* b1     = (const float*)d_in[5];
    const float* W2     = (const float*)d_in[6];
    const float* a_src2 = (const float*)d_in[7];
    const float* a_dst2 = (const float*)d_in[8];
    const float* b2     = (const float*)d_in[9];
    const float* Wl     = (const float*)d_in[10];
    const float* bl     = (const float*)d_in[11];

    const int N = in_sizes[0] / 128;
    const int E = in_sizes[1] / 2;
    const int* src = ei;
    const int* dst = ei + E;
    const int nbuck = (N + BSIZE - 1) >> BSHIFT;
    const int CB = (E + CEPB - 1) / CEPB;   // must be <= 256

    char* p = (char*)d_ws;
    auto alloc = [&](size_t bytes) -> void* {
        void* r = (void*)p;
        p += (bytes + 255) & ~(size_t)255;
        return r;
    };
    int*      offs        = (int*)alloc((size_t)(N + 1) * 4);
    int*      bucketCount = (int*)alloc(256 * 4);
    int*      blockHist   = (int*)alloc(256 * CBPAD * 4);
    unsigned* ebuf        = (unsigned*)alloc((size_t)nbuck * CB * ECAP * 4);
    int*      csr         = (int*)alloc((size_t)E * 4);
    __bf16*   hbf         = (__bf16*)alloc((size_t)N * 64 * 2);  // layer-1 h
    __bf16*   hbf2        = (__bf16*)alloc((size_t)N * 64 * 2);  // layer-2 h
    float*    as_         = (float*)alloc((size_t)N * 4);
    float*    ad_         = (float*)alloc((size_t)N * 4);
    float*    as2_        = (float*)alloc((size_t)N * 4);
    float*    ad2_        = (float*)alloc((size_t)N * 4);

    hipMemsetAsync(bucketCount, 0, 256 * 4, stream);

    const int nTiles = (N + 63) / 64;

    fused_hist_gemm<<<CB + 1024, 256, 0, stream>>>(
        src, dst, bucketCount, blockHist, ebuf, E, CB,
        x, W1, a_src1, a_dst1, hbf, as_, ad_, N, nTiles);
    bucket_fill<<<nbuck, 1024, 0, stream>>>(ebuf, blockHist, bucketCount,
                                            offs, csr, N, E, CB);
    agg_gemm2<<<nTiles, 256, 0, stream>>>(hbf, as_, ad_, b1, offs, csr,
                                          W2, a_src2, a_dst2, hbf2, as2_, ad2_, N);
    agg_final<<<nTiles, 256, 0, stream>>>(hbf2, as2_, ad2_, b2, offs, csr,
                                          Wl, bl, (float*)d_out, N);
}

// Round 9
// 284.433 us; speedup vs baseline: 1.1755x; 1.1755x over previous
//
#include <hip/hip_runtime.h>
#include <math.h>

// ---------------------------------------------------------------------------
// GAT x2 + linear + log_softmax on MI355X. R20.
//   - R19 post-mortem: fusing gather with block-granular MFMA halved resident
//     gather waves (72->35% occ) -> gather throughput halved (2.1->1.1 TB/s).
//     LESSON: keep gather kernels standalone, 1 wave/node. Reverted to R17.
//   - R20: LINEARITY. Aggregation commutes with the linear map:
//       out2 = segsum(a*(x2@W2)[src])+b2 = (segsum(a*x2[src]))@W2+b2
//       logits = y@(W2@Wl) + (b2@Wl+bl) = y@Wc + bc
//       alpha_s2 = x2@(W2@a_src2) = x2@u2  (rank-1)
//     => the per-node 64x64 W2 GEMM (gemm_mfma2 kernel + 25.6MB round-trip)
//     is DELETED. Precompute Wc/bc/u2/v2 in one extra block of kernel 1.
//     agg1 gains a tiny epilogue computing as2/ad2 = x2row . u2/v2.
//   - Pipeline: fused(+precompute) -> bucket_fill -> agg1 -> agg2 -> final.
// ---------------------------------------------------------------------------

#define NEG_SLOPE 0.2f
#define NEG_BIG -3.0e38f

#define BSHIFT 9
#define BSIZE 512            // nodes per bucket
#define CEPB 8192            // edges per chunk block
#define ECAP 112             // ebuf records per (bucket,chunk) slot
#define CBPAD 256            // blockHist row stride

typedef __bf16 bf16x8 __attribute__((ext_vector_type(8)));
typedef __bf16 bf16x4 __attribute__((ext_vector_type(4)));
typedef float f32x4 __attribute__((ext_vector_type(4)));

__device__ __forceinline__ float lrelu(float x) {
    return x >= 0.f ? x : NEG_SLOPE * x;
}

__device__ __forceinline__ int wave_incl_scan(int v, int lane) {
#pragma unroll
    for (int d = 1; d < 64; d <<= 1) {
        int t = __shfl_up(v, d, 64);
        if (lane >= d) v += t;
    }
    return v;
}

// ------- fused: hist+place || gemm1 (K=128, fp32 A hi/lo) || precompute ----

__global__ __launch_bounds__(256) void fused_hist_gemm(
        const int* __restrict__ src, const int* __restrict__ dst,
        int* __restrict__ bucketCount, int* __restrict__ blockHist,
        unsigned* __restrict__ ebuf, int E, int CB,
        const float* __restrict__ X, const float* __restrict__ W,
        const float* __restrict__ a_src, const float* __restrict__ a_dst,
        __bf16* __restrict__ Hout, float* __restrict__ as_, float* __restrict__ ad_,
        int N, int nTiles,
        const float* __restrict__ W2g, const float* __restrict__ Wlg,
        const float* __restrict__ blg, const float* __restrict__ b2g,
        const float* __restrict__ a_src2, const float* __restrict__ a_dst2,
        float* __restrict__ Wc, float* __restrict__ bc,
        float* __restrict__ u2, float* __restrict__ v2) {
    constexpr int K = 128;
    __shared__ __bf16 Whi[64][K + 8];
    __shared__ __bf16 Wlo[64][K + 8];
    __shared__ int hist[256];

    if (blockIdx.x < (unsigned)CB) {
        // ---- hist+place path: LDS rank capture, direct slotted ebuf write --
        const int t = threadIdx.x;
        hist[t] = 0;
        __syncthreads();
        const int c = blockIdx.x;
        const int e0 = c * CEPB;
        const int e1 = min(e0 + CEPB, E);
        int rr[CEPB / 256];
#pragma unroll
        for (int i = 0; i < CEPB / 256; ++i) {
            int e = e0 + i * 256 + t;
            if (e < e1) rr[i] = atomicAdd(&hist[dst[e] >> BSHIFT], 1);
        }
        __syncthreads();
        int hv = hist[t];
        blockHist[t * CBPAD + c] = hv;                    // plain store
        if (hv > 0) atomicAdd(&bucketCount[t], hv);       // fire-and-forget
#pragma unroll
        for (int i = 0; i < CEPB / 256; ++i) {
            int e = e0 + i * 256 + t;
            if (e < e1) {
                int d = dst[e];                            // L1/L2 hot
                int b = d >> BSHIFT;
                ebuf[((size_t)b * CB + c) * ECAP + rr[i]] =
                    ((unsigned)src[e] << BSHIFT) | (unsigned)(d & (BSIZE - 1));
            }
        }
        return;
    }

    if (blockIdx.x == (unsigned)(CB + 1024)) {
        // ---- precompute block: Wc = W2@Wl, bc = b2@Wl+bl, u2/v2 = W2@a_* --
        const int t = threadIdx.x;
        for (int idx = t; idx < 64 * 40; idx += 256) {
            int k = idx / 40, c = idx - k * 40;
            float s = 0.f;
            for (int j = 0; j < 64; ++j) s += W2g[k * 64 + j] * Wlg[j * 40 + c];
            Wc[idx] = s;
        }
        if (t < 40) {
            float s = blg[t];
            for (int j = 0; j < 64; ++j) s += b2g[j] * Wlg[j * 40 + t];
            bc[t] = s;
        }
        if (t < 64) {
            float su = 0.f, sv = 0.f;
            for (int j = 0; j < 64; ++j) {
                float w = W2g[t * 64 + j];
                su += w * a_src2[j];
                sv += w * a_dst2[j];
            }
            u2[t] = su;
            v2[t] = sv;
        }
        return;
    }

    // ---- gemm path ----
    const int gbid = blockIdx.x - CB;
    for (int idx = threadIdx.x; idx < K * 64; idx += 256) {
        int k = idx >> 6, n = idx & 63;
        float w = W[idx];
        __bf16 hi = (__bf16)w;
        Whi[n][k] = hi;
        Wlo[n][k] = (__bf16)(w - (float)hi);
    }
    __syncthreads();

    const int lane  = threadIdx.x & 63;
    const int wave  = threadIdx.x >> 6;
    const int row16 = lane & 15;
    const int quad  = lane >> 4;

    float asv[4], adv[4];
#pragma unroll
    for (int t = 0; t < 4; ++t) {
        asv[t] = a_src[t * 16 + row16];
        adv[t] = a_dst[t * 16 + row16];
    }

    for (int tile = gbid; tile < nTiles; tile += 1024) {
        const int nbase = tile * 64;
        int gn = nbase + wave * 16 + row16;
        if (gn >= N) gn = N - 1;
        const float* __restrict__ xp = X + (size_t)gn * K + quad * 8;

        float4 xv[K / 16];
#pragma unroll
        for (int c = 0; c < K / 32; ++c) {
            xv[2 * c]     = *(const float4*)(xp + c * 32);
            xv[2 * c + 1] = *(const float4*)(xp + c * 32 + 4);
        }

        f32x4 acc[4] = {{0.f, 0.f, 0.f, 0.f}, {0.f, 0.f, 0.f, 0.f},
                        {0.f, 0.f, 0.f, 0.f}, {0.f, 0.f, 0.f, 0.f}};
#pragma unroll
        for (int kc = 0; kc < K; kc += 32) {
            float xs[8];
            *(float4*)&xs[0] = xv[kc / 16];
            *(float4*)&xs[4] = xv[kc / 16 + 1];
            bf16x8 ahi, alo;
#pragma unroll
            for (int j = 0; j < 8; ++j) {
                __bf16 hi = (__bf16)xs[j];
                ahi[j] = hi;
                alo[j] = (__bf16)(xs[j] - (float)hi);
            }
#pragma unroll
            for (int t = 0; t < 4; ++t) {
                bf16x8 bhi = *(const bf16x8*)&Whi[t * 16 + row16][kc + quad * 8];
                bf16x8 blo = *(const bf16x8*)&Wlo[t * 16 + row16][kc + quad * 8];
                acc[t] = __builtin_amdgcn_mfma_f32_16x16x32_bf16(ahi, bhi, acc[t], 0, 0, 0);
                acc[t] = __builtin_amdgcn_mfma_f32_16x16x32_bf16(ahi, blo, acc[t], 0, 0, 0);
                acc[t] = __builtin_amdgcn_mfma_f32_16x16x32_bf16(alo, bhi, acc[t], 0, 0, 0);
            }
        }

        float ps[4] = {0.f, 0.f, 0.f, 0.f};
        float pd[4] = {0.f, 0.f, 0.f, 0.f};
#pragma unroll
        for (int t = 0; t < 4; ++t) {
#pragma unroll
            for (int r = 0; r < 4; ++r) {
                int gm = nbase + wave * 16 + quad * 4 + r;
                if (gm < N) Hout[(size_t)gm * 64 + t * 16 + row16] = (__bf16)acc[t][r];
                ps[r] = fmaf(acc[t][r], asv[t], ps[r]);
                pd[r] = fmaf(acc[t][r], adv[t], pd[r]);
            }
        }
#pragma unroll
        for (int r = 0; r < 4; ++r) {
#pragma unroll
            for (int d = 1; d < 16; d <<= 1) {
                ps[r] += __shfl_xor(ps[r], d, 64);
                pd[r] += __shfl_xor(pd[r], d, 64);
            }
        }
        if (row16 == 0) {
#pragma unroll
            for (int r = 0; r < 4; ++r) {
                int gm = nbase + wave * 16 + quad * 4 + r;
                if (gm < N) { as_[gm] = ps[r]; ad_[gm] = pd[r]; }
            }
        }
    }
}

// ---------------- per-bucket: gbase + offs + csr fill (LDS ranks) ----------

__global__ __launch_bounds__(1024) void bucket_fill(const unsigned* __restrict__ ebuf,
                                                    const int* __restrict__ blockHist,
                                                    const int* __restrict__ bucketCount,
                                                    int* __restrict__ offs,
                                                    int* __restrict__ csr,
                                                    int N, int E, int CB) {
    __shared__ int hist[512], excls[512], bhist_s[256], wsum[16], gsum[16];
    const int b = blockIdx.x;
    const int t = threadIdx.x;       // 0..1023
    const int lane = t & 63;
    const int w = t >> 6;            // 0..15

    // gbase = sum of bucketCount[0..b-1] (waves 0..3 carry data)
    int v = (t < 256 && t < b) ? bucketCount[t] : 0;
#pragma unroll
    for (int d = 32; d; d >>= 1) v += __shfl_xor(v, d, 64);
    if (lane == 0) gsum[w] = v;
    if (t < 512) hist[t] = 0;
    if (t < 256) bhist_s[t] = blockHist[b * CBPAD + t];
    if (b == 0 && t == 0) offs[N] = E;
    __syncthreads();
    int gbase = 0;
#pragma unroll
    for (int i = 0; i < 16; ++i) gbase += gsum[i];

    // phase 1: node-degree histogram with register rank capture.
    int rr[32];
#pragma unroll
    for (int ci = 0; ci < 16; ++ci) {
        int c = w + ci * 16;
        int cnt = (c < CB) ? bhist_s[c] : 0;
        const unsigned* __restrict__ ep = ebuf + ((size_t)b * CB + c) * ECAP;
#pragma unroll
        for (int ri = 0; ri < 2; ++ri) {
            int idx = ri * 64 + lane;
            if (idx < cnt) {
                unsigned rec = ep[idx];
                rr[ci * 2 + ri] = atomicAdd(&hist[rec & (BSIZE - 1)], 1);
            }
        }
    }
    __syncthreads();

    // phase 2: 512-entry exclusive scan (waves 0..7) -> offs
    int hv = (t < 512) ? hist[t] : 0;
    int incl = wave_incl_scan(hv, lane);
    if (lane == 63 && w < 8) wsum[w] = incl;
    __syncthreads();
    if (t < 512) {
        int pre = 0;
#pragma unroll
        for (int i = 0; i < 8; ++i) pre += (i < w) ? wsum[i] : 0;
        int excl = incl - hv + pre;
        int n = b * BSIZE + t;
        if (n < N) offs[n] = gbase + excl;
        excls[t] = excl;
    }
    __syncthreads();

    // phase 3: write csr (re-read ebuf region, L2-hot)
#pragma unroll
    for (int ci = 0; ci < 16; ++ci) {
        int c = w + ci * 16;
        int cnt = (c < CB) ? bhist_s[c] : 0;
        const unsigned* __restrict__ ep = ebuf + ((size_t)b * CB + c) * ECAP;
#pragma unroll
        for (int ri = 0; ri < 2; ++ri) {
            int idx = ri * 64 + lane;
            if (idx < cnt) {
                unsigned rec = ep[idx];
                csr[gbase + excls[rec & (BSIZE - 1)] + rr[ci * 2 + ri]] =
                    (int)(rec >> BSHIFT);
            }
        }
    }
}

// ------------- fused segment softmax + aggregation (4x16, 8-deep MLP) ------
// Optional epilogue (u2 != nullptr): as_out/ad_out = x2row . u2/v2

__global__ __launch_bounds__(256) void gat_agg(const __bf16* __restrict__ h,
                                               const float* __restrict__ as_,
                                               const float* __restrict__ ad_,
                                               const float* __restrict__ bias,
                                               const int* __restrict__ offs,
                                               const int* __restrict__ csr,
                                               __bf16* __restrict__ out,
                                               int N, int do_relu,
                                               const float* __restrict__ u2,
                                               const float* __restrict__ v2,
                                               float* __restrict__ as_out,
                                               float* __restrict__ ad_out) {
    int gtid = blockIdx.x * blockDim.x + threadIdx.x;
    int n = __builtin_amdgcn_readfirstlane(gtid >> 6);
    if (n >= N) return;
    const int lane = threadIdx.x & 63;
    const int g  = lane >> 4;   // edge group 0..3
    const int fl = lane & 15;   // feature quad index

    int beg = offs[n], end = offs[n + 1];
    float adn = ad_[n];
    float p_self = __expf(lrelu(as_[n] + adn));

    float den = p_self;
    float ax, ay, az, aw;
    {
        bf16x4 t = *(const bf16x4*)(h + (size_t)n * 64 + fl * 4);
        float m0 = (g == 0) ? p_self : 0.f;
        ax = m0 * (float)t[0];
        ay = m0 * (float)t[1];
        az = m0 * (float)t[2];
        aw = m0 * (float)t[3];
    }

    for (int c0 = beg; c0 < end; c0 += 64) {
        int cnt = end - c0;
        if (cnt > 64) cnt = 64;
        int   s_l = (lane < cnt) ? csr[c0 + lane] : 0;
        float p_l = (lane < cnt) ? __expf(lrelu(as_[s_l] + adn)) : 0.f;
        float csum = p_l;
#pragma unroll
        for (int d = 32; d; d >>= 1) csum += __shfl_xor(csum, d, 64);
        den += csum;

        // 8 independent gathers in flight per iteration (32 edges).
        int rounds = (cnt + 3) >> 2;
        for (int r = 0; r < rounds; r += 8) {
            int s[8];
#pragma unroll
            for (int i = 0; i < 8; ++i) s[i] = __shfl(s_l, (r + i) * 4 + g, 64);
            bf16x4 hv[8];
#pragma unroll
            for (int i = 0; i < 8; ++i)
                hv[i] = *(const bf16x4*)(h + (size_t)s[i] * 64 + fl * 4);
            float w[8];
#pragma unroll
            for (int i = 0; i < 8; ++i) w[i] = __shfl(p_l, (r + i) * 4 + g, 64);
#pragma unroll
            for (int i = 0; i < 8; ++i) {
                ax = fmaf(w[i], (float)hv[i][0], ax);
                ay = fmaf(w[i], (float)hv[i][1], ay);
                az = fmaf(w[i], (float)hv[i][2], az);
                aw = fmaf(w[i], (float)hv[i][3], aw);
            }
        }
    }

#pragma unroll
    for (int d = 16; d <= 32; d <<= 1) {
        ax += __shfl_xor(ax, d, 64);
        ay += __shfl_xor(ay, d, 64);
        az += __shfl_xor(az, d, 64);
        aw += __shfl_xor(aw, d, 64);
    }
    if (g == 0) {
        float inv = 1.f / (den + 1e-16f);
        const float4 b4 = *(const float4*)(bias + fl * 4);
        float o0 = fmaf(ax, inv, b4.x);
        float o1 = fmaf(ay, inv, b4.y);
        float o2 = fmaf(az, inv, b4.z);
        float o3 = fmaf(aw, inv, b4.w);
        if (do_relu) {
            o0 = fmaxf(o0, 0.f); o1 = fmaxf(o1, 0.f);
            o2 = fmaxf(o2, 0.f); o3 = fmaxf(o3, 0.f);
        }
        bf16x4 ov;
        ov[0] = (__bf16)o0; ov[1] = (__bf16)o1;
        ov[2] = (__bf16)o2; ov[3] = (__bf16)o3;
        *(bf16x4*)(out + (size_t)n * 64 + fl * 4) = ov;

        if (u2 != nullptr) {
            const float4 u4 = *(const float4*)(u2 + fl * 4);
            const float4 v4 = *(const float4*)(v2 + fl * 4);
            float pu = o0 * u4.x + o1 * u4.y + o2 * u4.z + o3 * u4.w;
            float pv = o0 * v4.x + o1 * v4.y + o2 * v4.z + o3 * v4.w;
#pragma unroll
            for (int d = 1; d <= 8; d <<= 1) {
                pu += __shfl_xor(pu, d, 64);
                pv += __shfl_xor(pv, d, 64);
            }
            if (fl == 0) { as_out[n] = pu; ad_out[n] = pv; }
        }
    }
}

// ---------------- final linear (y@Wc + bc, 2-term) + log_softmax -----------

__global__ __launch_bounds__(256) void final_lsm(const __bf16* __restrict__ h,
                                                 const float* __restrict__ Wl,
                                                 const float* __restrict__ bl,
                                                 float* __restrict__ out,
                                                 int N, int nTiles) {
    __shared__ __bf16 Whi[48][72];
    __shared__ __bf16 Wlo[48][72];
    __shared__ float bls[48];
    for (int idx = threadIdx.x; idx < 48 * 64; idx += 256) {
        int c = idx >> 6, k = idx & 63;
        float w = (c < 40) ? Wl[k * 40 + c] : 0.f;
        __bf16 hi = (__bf16)w;
        Whi[c][k] = hi;
        Wlo[c][k] = (__bf16)(w - (float)hi);
    }
    if (threadIdx.x < 48) bls[threadIdx.x] = (threadIdx.x < 40) ? bl[threadIdx.x] : 0.f;
    __syncthreads();

    const int lane  = threadIdx.x & 63;
    const int wave  = threadIdx.x >> 6;
    const int col16 = lane & 15;
    const int quad  = lane >> 4;

    for (int tile = blockIdx.x; tile < nTiles; tile += gridDim.x) {
        const int nbase = tile * 64;
        int gn = nbase + wave * 16 + col16;
        if (gn >= N) gn = N - 1;
        const __bf16* __restrict__ xp = h + (size_t)gn * 64 + quad * 8;
        bf16x8 a0 = *(const bf16x8*)(xp);
        bf16x8 a1 = *(const bf16x8*)(xp + 32);

        f32x4 acc[3] = {{0.f, 0.f, 0.f, 0.f}, {0.f, 0.f, 0.f, 0.f},
                        {0.f, 0.f, 0.f, 0.f}};
#pragma unroll
        for (int kc = 0; kc < 64; kc += 32) {
            bf16x8 a = (kc == 0) ? a0 : a1;
#pragma unroll
            for (int t = 0; t < 3; ++t) {
                bf16x8 bhi = *(const bf16x8*)&Whi[t * 16 + col16][kc + quad * 8];
                bf16x8 blo = *(const bf16x8*)&Wlo[t * 16 + col16][kc + quad * 8];
                acc[t] = __builtin_amdgcn_mfma_f32_16x16x32_bf16(a, bhi, acc[t], 0, 0, 0);
                acc[t] = __builtin_amdgcn_mfma_f32_16x16x32_bf16(a, blo, acc[t], 0, 0, 0);
            }
        }

#pragma unroll
        for (int r = 0; r < 4; ++r) {
            int gm = nbase + wave * 16 + quad * 4 + r;
            float l0 = acc[0][r] + bls[col16];
            float l1 = acc[1][r] + bls[16 + col16];
            float l2 = (col16 < 8) ? (acc[2][r] + bls[32 + col16]) : NEG_BIG;
            float mx = fmaxf(fmaxf(l0, l1), l2);
#pragma unroll
            for (int d = 1; d < 16; d <<= 1) mx = fmaxf(mx, __shfl_xor(mx, d, 64));
            float s = __expf(l0 - mx) + __expf(l1 - mx) +
                      ((col16 < 8) ? __expf(l2 - mx) : 0.f);
#pragma unroll
            for (int d = 1; d < 16; d <<= 1) s += __shfl_xor(s, d, 64);
            float lse = mx + __logf(s);
            if (gm < N) {
                out[(size_t)gm * 40 + col16]      = l0 - lse;
                out[(size_t)gm * 40 + 16 + col16] = l1 - lse;
                if (col16 < 8) out[(size_t)gm * 40 + 32 + col16] = l2 - lse;
            }
        }
    }
}

// ---------------- launch ----------------

extern "C" void kernel_launch(void* const* d_in, const int* in_sizes, int n_in,
                              void* d_out, int out_size, void* d_ws, size_t ws_size,
                              hipStream_t stream) {
    const float* x      = (const float*)d_in[0];
    const int*   ei     = (const int*)d_in[1];
    const float* W1     = (const float*)d_in[2];
    const float* a_src1 = (const float*)d_in[3];
    const float* a_dst1 = (const float*)d_in[4];
    const float* b1     = (const float*)d_in[5];
    const float* W2     = (const float*)d_in[6];
    const float* a_src2 = (const float*)d_in[7];
    const float* a_dst2 = (const float*)d_in[8];
    const float* b2     = (const float*)d_in[9];
    const float* Wl     = (const float*)d_in[10];
    const float* bl     = (const float*)d_in[11];

    const int N = in_sizes[0] / 128;
    const int E = in_sizes[1] / 2;
    const int* src = ei;
    const int* dst = ei + E;
    const int nbuck = (N + BSIZE - 1) >> BSHIFT;
    const int CB = (E + CEPB - 1) / CEPB;   // must be <= 256

    char* p = (char*)d_ws;
    auto alloc = [&](size_t bytes) -> void* {
        void* r = (void*)p;
        p += (bytes + 255) & ~(size_t)255;
        return r;
    };
    int*      offs        = (int*)alloc((size_t)(N + 1) * 4);
    int*      bucketCount = (int*)alloc(256 * 4);
    float*    zbias       = (float*)alloc(64 * 4);        // zeroed with bucketCount
    int*      blockHist   = (int*)alloc(256 * CBPAD * 4);
    unsigned* ebuf        = (unsigned*)alloc((size_t)nbuck * CB * ECAP * 4);
    int*      csr         = (int*)alloc((size_t)E * 4);
    __bf16*   hbf         = (__bf16*)alloc((size_t)N * 64 * 2);  // h1, then y
    __bf16*   habg        = (__bf16*)alloc((size_t)N * 64 * 2);  // x2 = agg1 out
    float*    as_         = (float*)alloc((size_t)N * 4);
    float*    ad_         = (float*)alloc((size_t)N * 4);
    float*    as2_        = (float*)alloc((size_t)N * 4);
    float*    ad2_        = (float*)alloc((size_t)N * 4);
    float*    Wc          = (float*)alloc(64 * 40 * 4);
    float*    bc          = (float*)alloc(40 * 4);
    float*    u2          = (float*)alloc(64 * 4);
    float*    v2          = (float*)alloc(64 * 4);

    // bucketCount (1024B) and zbias (256B) are adjacent -> one memset
    hipMemsetAsync(bucketCount, 0, 1024 + 256, stream);

    const int nTiles = (N + 63) / 64;
    int aggBlocks = (N * 64 + 255) / 256;

    fused_hist_gemm<<<CB + 1025, 256, 0, stream>>>(
        src, dst, bucketCount, blockHist, ebuf, E, CB,
        x, W1, a_src1, a_dst1, hbf, as_, ad_, N, nTiles,
        W2, Wl, bl, b2, a_src2, a_dst2, Wc, bc, u2, v2);
    bucket_fill<<<nbuck, 1024, 0, stream>>>(ebuf, blockHist, bucketCount,
                                            offs, csr, N, E, CB);
    gat_agg<<<aggBlocks, 256, 0, stream>>>(hbf, as_, ad_, b1, offs, csr, habg,
                                           N, 1, u2, v2, as2_, ad2_);
    gat_agg<<<aggBlocks, 256, 0, stream>>>(habg, as2_, ad2_, zbias, offs, csr, hbf,
                                           N, 0, nullptr, nullptr, nullptr, nullptr);
    final_lsm<<<nTiles, 256, 0, stream>>>(hbf, Wc, bc, (float*)d_out, N, nTiles);
}

// Round 10
// 274.951 us; speedup vs baseline: 1.2160x; 1.0345x over previous
//
#include <hip/hip_runtime.h>
#include <math.h>

// ---------------------------------------------------------------------------
// GAT x2 + linear + log_softmax on MI355X. R21.
//   - R20 post-mortem: linearity rewrite correct (gemm_mfma2 deleted, passed)
//     but the precompute block was a serial straggler (640 dependent global
//     loads/thread) -> fused kernel 51->63us (kernel dur = max over blocks).
//   - R21: precompute block stages W2/Wl into LDS first (REUSING the already
//     allocated Whi/Wlo arrays -> no extra LDS, gemm occupancy untouched),
//     coalesced; then computes Wc=W2@Wl, bc=b2@Wl+bl, u2/v2=W2@a_* from
//     LDS-hot data (~2-3us).
//   - Everything else identical to R20.
// ---------------------------------------------------------------------------

#define NEG_SLOPE 0.2f
#define NEG_BIG -3.0e38f

#define BSHIFT 9
#define BSIZE 512            // nodes per bucket
#define CEPB 8192            // edges per chunk block
#define ECAP 112             // ebuf records per (bucket,chunk) slot
#define CBPAD 256            // blockHist row stride

typedef __bf16 bf16x8 __attribute__((ext_vector_type(8)));
typedef __bf16 bf16x4 __attribute__((ext_vector_type(4)));
typedef float f32x4 __attribute__((ext_vector_type(4)));

__device__ __forceinline__ float lrelu(float x) {
    return x >= 0.f ? x : NEG_SLOPE * x;
}

__device__ __forceinline__ int wave_incl_scan(int v, int lane) {
#pragma unroll
    for (int d = 1; d < 64; d <<= 1) {
        int t = __shfl_up(v, d, 64);
        if (lane >= d) v += t;
    }
    return v;
}

// ------- fused: hist+place || gemm1 (K=128, fp32 A hi/lo) || precompute ----

__global__ __launch_bounds__(256) void fused_hist_gemm(
        const int* __restrict__ src, const int* __restrict__ dst,
        int* __restrict__ bucketCount, int* __restrict__ blockHist,
        unsigned* __restrict__ ebuf, int E, int CB,
        const float* __restrict__ X, const float* __restrict__ W,
        const float* __restrict__ a_src, const float* __restrict__ a_dst,
        __bf16* __restrict__ Hout, float* __restrict__ as_, float* __restrict__ ad_,
        int N, int nTiles,
        const float* __restrict__ W2g, const float* __restrict__ Wlg,
        const float* __restrict__ blg, const float* __restrict__ b2g,
        const float* __restrict__ a_src2, const float* __restrict__ a_dst2,
        float* __restrict__ Wc, float* __restrict__ bc,
        float* __restrict__ u2, float* __restrict__ v2) {
    constexpr int K = 128;
    __shared__ __bf16 Whi[64][K + 8];
    __shared__ __bf16 Wlo[64][K + 8];
    __shared__ int hist[256];

    if (blockIdx.x < (unsigned)CB) {
        // ---- hist+place path: LDS rank capture, direct slotted ebuf write --
        const int t = threadIdx.x;
        hist[t] = 0;
        __syncthreads();
        const int c = blockIdx.x;
        const int e0 = c * CEPB;
        const int e1 = min(e0 + CEPB, E);
        int rr[CEPB / 256];
#pragma unroll
        for (int i = 0; i < CEPB / 256; ++i) {
            int e = e0 + i * 256 + t;
            if (e < e1) rr[i] = atomicAdd(&hist[dst[e] >> BSHIFT], 1);
        }
        __syncthreads();
        int hv = hist[t];
        blockHist[t * CBPAD + c] = hv;                    // plain store
        if (hv > 0) atomicAdd(&bucketCount[t], hv);       // fire-and-forget
#pragma unroll
        for (int i = 0; i < CEPB / 256; ++i) {
            int e = e0 + i * 256 + t;
            if (e < e1) {
                int d = dst[e];                            // L1/L2 hot
                int b = d >> BSHIFT;
                ebuf[((size_t)b * CB + c) * ECAP + rr[i]] =
                    ((unsigned)src[e] << BSHIFT) | (unsigned)(d & (BSIZE - 1));
            }
        }
        return;
    }

    if (blockIdx.x == (unsigned)(CB + 1024)) {
        // ---- precompute block (LDS-staged): Wc=W2@Wl, bc=b2@Wl+bl,
        //      u2/v2 = W2@a_*. Reuse Whi/Wlo LDS as float scratch.
        const int t = threadIdx.x;
        float* W2s = (float*)&Whi[0][0];   // 64*64*4 = 16384 B <= 17408 B
        float* Wls = (float*)&Wlo[0][0];   // 64*40*4 = 10240 B <= 17408 B
        for (int idx = t; idx < 64 * 64; idx += 256) W2s[idx] = W2g[idx];
        for (int idx = t; idx < 64 * 40; idx += 256) Wls[idx] = Wlg[idx];
        __syncthreads();
        for (int idx = t; idx < 64 * 40; idx += 256) {
            int k = idx / 40, c = idx - k * 40;
            float s = 0.f;
#pragma unroll 8
            for (int j = 0; j < 64; ++j) s += W2s[k * 64 + j] * Wls[j * 40 + c];
            Wc[idx] = s;
        }
        if (t < 40) {
            float s = blg[t];
            for (int j = 0; j < 64; ++j) s += b2g[j] * Wls[j * 40 + t];
            bc[t] = s;
        }
        if (t >= 64 && t < 128) {
            int r = t - 64;
            float su = 0.f, sv = 0.f;
            for (int j = 0; j < 64; ++j) {
                float w = W2s[r * 64 + j];
                su += w * a_src2[j];
                sv += w * a_dst2[j];
            }
            u2[r] = su;
            v2[r] = sv;
        }
        return;
    }

    // ---- gemm path ----
    const int gbid = blockIdx.x - CB;
    for (int idx = threadIdx.x; idx < K * 64; idx += 256) {
        int k = idx >> 6, n = idx & 63;
        float w = W[idx];
        __bf16 hi = (__bf16)w;
        Whi[n][k] = hi;
        Wlo[n][k] = (__bf16)(w - (float)hi);
    }
    __syncthreads();

    const int lane  = threadIdx.x & 63;
    const int wave  = threadIdx.x >> 6;
    const int row16 = lane & 15;
    const int quad  = lane >> 4;

    float asv[4], adv[4];
#pragma unroll
    for (int t = 0; t < 4; ++t) {
        asv[t] = a_src[t * 16 + row16];
        adv[t] = a_dst[t * 16 + row16];
    }

    for (int tile = gbid; tile < nTiles; tile += 1024) {
        const int nbase = tile * 64;
        int gn = nbase + wave * 16 + row16;
        if (gn >= N) gn = N - 1;
        const float* __restrict__ xp = X + (size_t)gn * K + quad * 8;

        float4 xv[K / 16];
#pragma unroll
        for (int c = 0; c < K / 32; ++c) {
            xv[2 * c]     = *(const float4*)(xp + c * 32);
            xv[2 * c + 1] = *(const float4*)(xp + c * 32 + 4);
        }

        f32x4 acc[4] = {{0.f, 0.f, 0.f, 0.f}, {0.f, 0.f, 0.f, 0.f},
                        {0.f, 0.f, 0.f, 0.f}, {0.f, 0.f, 0.f, 0.f}};
#pragma unroll
        for (int kc = 0; kc < K; kc += 32) {
            float xs[8];
            *(float4*)&xs[0] = xv[kc / 16];
            *(float4*)&xs[4] = xv[kc / 16 + 1];
            bf16x8 ahi, alo;
#pragma unroll
            for (int j = 0; j < 8; ++j) {
                __bf16 hi = (__bf16)xs[j];
                ahi[j] = hi;
                alo[j] = (__bf16)(xs[j] - (float)hi);
            }
#pragma unroll
            for (int t = 0; t < 4; ++t) {
                bf16x8 bhi = *(const bf16x8*)&Whi[t * 16 + row16][kc + quad * 8];
                bf16x8 blo = *(const bf16x8*)&Wlo[t * 16 + row16][kc + quad * 8];
                acc[t] = __builtin_amdgcn_mfma_f32_16x16x32_bf16(ahi, bhi, acc[t], 0, 0, 0);
                acc[t] = __builtin_amdgcn_mfma_f32_16x16x32_bf16(ahi, blo, acc[t], 0, 0, 0);
                acc[t] = __builtin_amdgcn_mfma_f32_16x16x32_bf16(alo, bhi, acc[t], 0, 0, 0);
            }
        }

        float ps[4] = {0.f, 0.f, 0.f, 0.f};
        float pd[4] = {0.f, 0.f, 0.f, 0.f};
#pragma unroll
        for (int t = 0; t < 4; ++t) {
#pragma unroll
            for (int r = 0; r < 4; ++r) {
                int gm = nbase + wave * 16 + quad * 4 + r;
                if (gm < N) Hout[(size_t)gm * 64 + t * 16 + row16] = (__bf16)acc[t][r];
                ps[r] = fmaf(acc[t][r], asv[t], ps[r]);
                pd[r] = fmaf(acc[t][r], adv[t], pd[r]);
            }
        }
#pragma unroll
        for (int r = 0; r < 4; ++r) {
#pragma unroll
            for (int d = 1; d < 16; d <<= 1) {
                ps[r] += __shfl_xor(ps[r], d, 64);
                pd[r] += __shfl_xor(pd[r], d, 64);
            }
        }
        if (row16 == 0) {
#pragma unroll
            for (int r = 0; r < 4; ++r) {
                int gm = nbase + wave * 16 + quad * 4 + r;
                if (gm < N) { as_[gm] = ps[r]; ad_[gm] = pd[r]; }
            }
        }
    }
}

// ---------------- per-bucket: gbase + offs + csr fill (LDS ranks) ----------

__global__ __launch_bounds__(1024) void bucket_fill(const unsigned* __restrict__ ebuf,
                                                    const int* __restrict__ blockHist,
                                                    const int* __restrict__ bucketCount,
                                                    int* __restrict__ offs,
                                                    int* __restrict__ csr,
                                                    int N, int E, int CB) {
    __shared__ int hist[512], excls[512], bhist_s[256], wsum[16], gsum[16];
    const int b = blockIdx.x;
    const int t = threadIdx.x;       // 0..1023
    const int lane = t & 63;
    const int w = t >> 6;            // 0..15

    // gbase = sum of bucketCount[0..b-1] (waves 0..3 carry data)
    int v = (t < 256 && t < b) ? bucketCount[t] : 0;
#pragma unroll
    for (int d = 32; d; d >>= 1) v += __shfl_xor(v, d, 64);
    if (lane == 0) gsum[w] = v;
    if (t < 512) hist[t] = 0;
    if (t < 256) bhist_s[t] = blockHist[b * CBPAD + t];
    if (b == 0 && t == 0) offs[N] = E;
    __syncthreads();
    int gbase = 0;
#pragma unroll
    for (int i = 0; i < 16; ++i) gbase += gsum[i];

    // phase 1: node-degree histogram with register rank capture.
    int rr[32];
#pragma unroll
    for (int ci = 0; ci < 16; ++ci) {
        int c = w + ci * 16;
        int cnt = (c < CB) ? bhist_s[c] : 0;
        const unsigned* __restrict__ ep = ebuf + ((size_t)b * CB + c) * ECAP;
#pragma unroll
        for (int ri = 0; ri < 2; ++ri) {
            int idx = ri * 64 + lane;
            if (idx < cnt) {
                unsigned rec = ep[idx];
                rr[ci * 2 + ri] = atomicAdd(&hist[rec & (BSIZE - 1)], 1);
            }
        }
    }
    __syncthreads();

    // phase 2: 512-entry exclusive scan (waves 0..7) -> offs
    int hv = (t < 512) ? hist[t] : 0;
    int incl = wave_incl_scan(hv, lane);
    if (lane == 63 && w < 8) wsum[w] = incl;
    __syncthreads();
    if (t < 512) {
        int pre = 0;
#pragma unroll
        for (int i = 0; i < 8; ++i) pre += (i < w) ? wsum[i] : 0;
        int excl = incl - hv + pre;
        int n = b * BSIZE + t;
        if (n < N) offs[n] = gbase + excl;
        excls[t] = excl;
    }
    __syncthreads();

    // phase 3: write csr (re-read ebuf region, L2-hot)
#pragma unroll
    for (int ci = 0; ci < 16; ++ci) {
        int c = w + ci * 16;
        int cnt = (c < CB) ? bhist_s[c] : 0;
        const unsigned* __restrict__ ep = ebuf + ((size_t)b * CB + c) * ECAP;
#pragma unroll
        for (int ri = 0; ri < 2; ++ri) {
            int idx = ri * 64 + lane;
            if (idx < cnt) {
                unsigned rec = ep[idx];
                csr[gbase + excls[rec & (BSIZE - 1)] + rr[ci * 2 + ri]] =
                    (int)(rec >> BSHIFT);
            }
        }
    }
}

// ------------- fused segment softmax + aggregation (4x16, 8-deep MLP) ------
// Optional epilogue (u2 != nullptr): as_out/ad_out = x2row . u2/v2

__global__ __launch_bounds__(256) void gat_agg(const __bf16* __restrict__ h,
                                               const float* __restrict__ as_,
                                               const float* __restrict__ ad_,
                                               const float* __restrict__ bias,
                                               const int* __restrict__ offs,
                                               const int* __restrict__ csr,
                                               __bf16* __restrict__ out,
                                               int N, int do_relu,
                                               const float* __restrict__ u2,
                                               const float* __restrict__ v2,
                                               float* __restrict__ as_out,
                                               float* __restrict__ ad_out) {
    int gtid = blockIdx.x * blockDim.x + threadIdx.x;
    int n = __builtin_amdgcn_readfirstlane(gtid >> 6);
    if (n >= N) return;
    const int lane = threadIdx.x & 63;
    const int g  = lane >> 4;   // edge group 0..3
    const int fl = lane & 15;   // feature quad index

    int beg = offs[n], end = offs[n + 1];
    float adn = ad_[n];
    float p_self = __expf(lrelu(as_[n] + adn));

    float den = p_self;
    float ax, ay, az, aw;
    {
        bf16x4 t = *(const bf16x4*)(h + (size_t)n * 64 + fl * 4);
        float m0 = (g == 0) ? p_self : 0.f;
        ax = m0 * (float)t[0];
        ay = m0 * (float)t[1];
        az = m0 * (float)t[2];
        aw = m0 * (float)t[3];
    }

    for (int c0 = beg; c0 < end; c0 += 64) {
        int cnt = end - c0;
        if (cnt > 64) cnt = 64;
        int   s_l = (lane < cnt) ? csr[c0 + lane] : 0;
        float p_l = (lane < cnt) ? __expf(lrelu(as_[s_l] + adn)) : 0.f;
        float csum = p_l;
#pragma unroll
        for (int d = 32; d; d >>= 1) csum += __shfl_xor(csum, d, 64);
        den += csum;

        // 8 independent gathers in flight per iteration (32 edges).
        int rounds = (cnt + 3) >> 2;
        for (int r = 0; r < rounds; r += 8) {
            int s[8];
#pragma unroll
            for (int i = 0; i < 8; ++i) s[i] = __shfl(s_l, (r + i) * 4 + g, 64);
            bf16x4 hv[8];
#pragma unroll
            for (int i = 0; i < 8; ++i)
                hv[i] = *(const bf16x4*)(h + (size_t)s[i] * 64 + fl * 4);
            float w[8];
#pragma unroll
            for (int i = 0; i < 8; ++i) w[i] = __shfl(p_l, (r + i) * 4 + g, 64);
#pragma unroll
            for (int i = 0; i < 8; ++i) {
                ax = fmaf(w[i], (float)hv[i][0], ax);
                ay = fmaf(w[i], (float)hv[i][1], ay);
                az = fmaf(w[i], (float)hv[i][2], az);
                aw = fmaf(w[i], (float)hv[i][3], aw);
            }
        }
    }

#pragma unroll
    for (int d = 16; d <= 32; d <<= 1) {
        ax += __shfl_xor(ax, d, 64);
        ay += __shfl_xor(ay, d, 64);
        az += __shfl_xor(az, d, 64);
        aw += __shfl_xor(aw, d, 64);
    }
    if (g == 0) {
        float inv = 1.f / (den + 1e-16f);
        const float4 b4 = *(const float4*)(bias + fl * 4);
        float o0 = fmaf(ax, inv, b4.x);
        float o1 = fmaf(ay, inv, b4.y);
        float o2 = fmaf(az, inv, b4.z);
        float o3 = fmaf(aw, inv, b4.w);
        if (do_relu) {
            o0 = fmaxf(o0, 0.f); o1 = fmaxf(o1, 0.f);
            o2 = fmaxf(o2, 0.f); o3 = fmaxf(o3, 0.f);
        }
        bf16x4 ov;
        ov[0] = (__bf16)o0; ov[1] = (__bf16)o1;
        ov[2] = (__bf16)o2; ov[3] = (__bf16)o3;
        *(bf16x4*)(out + (size_t)n * 64 + fl * 4) = ov;

        if (u2 != nullptr) {
            const float4 u4 = *(const float4*)(u2 + fl * 4);
            const float4 v4 = *(const float4*)(v2 + fl * 4);
            float pu = o0 * u4.x + o1 * u4.y + o2 * u4.z + o3 * u4.w;
            float pv = o0 * v4.x + o1 * v4.y + o2 * v4.z + o3 * v4.w;
#pragma unroll
            for (int d = 1; d <= 8; d <<= 1) {
                pu += __shfl_xor(pu, d, 64);
                pv += __shfl_xor(pv, d, 64);
            }
            if (fl == 0) { as_out[n] = pu; ad_out[n] = pv; }
        }
    }
}

// ---------------- final linear (y@Wc + bc, 2-term) + log_softmax -----------

__global__ __launch_bounds__(256) void final_lsm(const __bf16* __restrict__ h,
                                                 const float* __restrict__ Wl,
                                                 const float* __restrict__ bl,
                                                 float* __restrict__ out,
                                                 int N, int nTiles) {
    __shared__ __bf16 Whi[48][72];
    __shared__ __bf16 Wlo[48][72];
    __shared__ float bls[48];
    for (int idx = threadIdx.x; idx < 48 * 64; idx += 256) {
        int c = idx >> 6, k = idx & 63;
        float w = (c < 40) ? Wl[k * 40 + c] : 0.f;
        __bf16 hi = (__bf16)w;
        Whi[c][k] = hi;
        Wlo[c][k] = (__bf16)(w - (float)hi);
    }
    if (threadIdx.x < 48) bls[threadIdx.x] = (threadIdx.x < 40) ? bl[threadIdx.x] : 0.f;
    __syncthreads();

    const int lane  = threadIdx.x & 63;
    const int wave  = threadIdx.x >> 6;
    const int col16 = lane & 15;
    const int quad  = lane >> 4;

    for (int tile = blockIdx.x; tile < nTiles; tile += gridDim.x) {
        const int nbase = tile * 64;
        int gn = nbase + wave * 16 + col16;
        if (gn >= N) gn = N - 1;
        const __bf16* __restrict__ xp = h + (size_t)gn * 64 + quad * 8;
        bf16x8 a0 = *(const bf16x8*)(xp);
        bf16x8 a1 = *(const bf16x8*)(xp + 32);

        f32x4 acc[3] = {{0.f, 0.f, 0.f, 0.f}, {0.f, 0.f, 0.f, 0.f},
                        {0.f, 0.f, 0.f, 0.f}};
#pragma unroll
        for (int kc = 0; kc < 64; kc += 32) {
            bf16x8 a = (kc == 0) ? a0 : a1;
#pragma unroll
            for (int t = 0; t < 3; ++t) {
                bf16x8 bhi = *(const bf16x8*)&Whi[t * 16 + col16][kc + quad * 8];
                bf16x8 blo = *(const bf16x8*)&Wlo[t * 16 + col16][kc + quad * 8];
                acc[t] = __builtin_amdgcn_mfma_f32_16x16x32_bf16(a, bhi, acc[t], 0, 0, 0);
                acc[t] = __builtin_amdgcn_mfma_f32_16x16x32_bf16(a, blo, acc[t], 0, 0, 0);
            }
        }

#pragma unroll
        for (int r = 0; r < 4; ++r) {
            int gm = nbase + wave * 16 + quad * 4 + r;
            float l0 = acc[0][r] + bls[col16];
            float l1 = acc[1][r] + bls[16 + col16];
            float l2 = (col16 < 8) ? (acc[2][r] + bls[32 + col16]) : NEG_BIG;
            float mx = fmaxf(fmaxf(l0, l1), l2);
#pragma unroll
            for (int d = 1; d < 16; d <<= 1) mx = fmaxf(mx, __shfl_xor(mx, d, 64));
            float s = __expf(l0 - mx) + __expf(l1 - mx) +
                      ((col16 < 8) ? __expf(l2 - mx) : 0.f);
#pragma unroll
            for (int d = 1; d < 16; d <<= 1) s += __shfl_xor(s, d, 64);
            float lse = mx + __logf(s);
            if (gm < N) {
                out[(size_t)gm * 40 + col16]      = l0 - lse;
                out[(size_t)gm * 40 + 16 + col16] = l1 - lse;
                if (col16 < 8) out[(size_t)gm * 40 + 32 + col16] = l2 - lse;
            }
        }
    }
}

// ---------------- launch ----------------

extern "C" void kernel_launch(void* const* d_in, const int* in_sizes, int n_in,
                              void* d_out, int out_size, void* d_ws, size_t ws_size,
                              hipStream_t stream) {
    const float* x      = (const float*)d_in[0];
    const int*   ei     = (const int*)d_in[1];
    const float* W1     = (const float*)d_in[2];
    const float* a_src1 = (const float*)d_in[3];
    const float* a_dst1 = (const float*)d_in[4];
    const float* b1     = (const float*)d_in[5];
    const float* W2     = (const float*)d_in[6];
    const float* a_src2 = (const float*)d_in[7];
    const float* a_dst2 = (const float*)d_in[8];
    const float* b2     = (const float*)d_in[9];
    const float* Wl     = (const float*)d_in[10];
    const float* bl     = (const float*)d_in[11];

    const int N = in_sizes[0] / 128;
    const int E = in_sizes[1] / 2;
    const int* src = ei;
    const int* dst = ei + E;
    const int nbuck = (N + BSIZE - 1) >> BSHIFT;
    const int CB = (E + CEPB - 1) / CEPB;   // must be <= 256

    char* p = (char*)d_ws;
    auto alloc = [&](size_t bytes) -> void* {
        void* r = (void*)p;
        p += (bytes + 255) & ~(size_t)255;
        return r;
    };
    int*      offs        = (int*)alloc((size_t)(N + 1) * 4);
    int*      bucketCount = (int*)alloc(256 * 4);
    float*    zbias       = (float*)alloc(64 * 4);        // zeroed with bucketCount
    int*      blockHist   = (int*)alloc(256 * CBPAD * 4);
    unsigned* ebuf        = (unsigned*)alloc((size_t)nbuck * CB * ECAP * 4);
    int*      csr         = (int*)alloc((size_t)E * 4);
    __bf16*   hbf         = (__bf16*)alloc((size_t)N * 64 * 2);  // h1, then y
    __bf16*   habg        = (__bf16*)alloc((size_t)N * 64 * 2);  // x2 = agg1 out
    float*    as_         = (float*)alloc((size_t)N * 4);
    float*    ad_         = (float*)alloc((size_t)N * 4);
    float*    as2_        = (float*)alloc((size_t)N * 4);
    float*    ad2_        = (float*)alloc((size_t)N * 4);
    float*    Wc          = (float*)alloc(64 * 40 * 4);
    float*    bc          = (float*)alloc(40 * 4);
    float*    u2          = (float*)alloc(64 * 4);
    float*    v2          = (float*)alloc(64 * 4);

    // bucketCount (1024B) and zbias (256B) are adjacent -> one memset
    hipMemsetAsync(bucketCount, 0, 1024 + 256, stream);

    const int nTiles = (N + 63) / 64;
    int aggBlocks = (N * 64 + 255) / 256;

    fused_hist_gemm<<<CB + 1025, 256, 0, stream>>>(
        src, dst, bucketCount, blockHist, ebuf, E, CB,
        x, W1, a_src1, a_dst1, hbf, as_, ad_, N, nTiles,
        W2, Wl, bl, b2, a_src2, a_dst2, Wc, bc, u2, v2);
    bucket_fill<<<nbuck, 1024, 0, stream>>>(ebuf, blockHist, bucketCount,
                                            offs, csr, N, E, CB);
    gat_agg<<<aggBlocks, 256, 0, stream>>>(hbf, as_, ad_, b1, offs, csr, habg,
                                           N, 1, u2, v2, as2_, ad2_);
    gat_agg<<<aggBlocks, 256, 0, stream>>>(habg, as2_, ad2_, zbias, offs, csr, hbf,
                                           N, 0, nullptr, nullptr, nullptr, nullptr);
    final_lsm<<<nTiles, 256, 0, stream>>>(hbf, Wc, bc, (float*)d_out, N, nTiles);
}

// Round 11
// 269.767 us; speedup vs baseline: 1.2394x; 1.0192x over previous
//
#include <hip/hip_runtime.h>
#include <math.h>

// ---------------------------------------------------------------------------
// GAT x2 + linear + log_softmax on MI355X. R22.
//   - R21 post-mortem (274.95 best): agg1 epilogue +7us = u2/v2 loads inside
//     the g==0 tail (serial latency per node). final_lsm stages Wl with
//     160B-strided UNCOALESCED reads (3072 scattered 4B reqs/block x 1563
//     blocks) - suspected 10-30us hidden cost. bucket_fill re-reads ebuf.
//   - R22: (1) final_lsm: coalesced linear Wl staging, transpose on LDS
//     write; (2) agg: hoist u4/v4/b4 loads to entry (latency hides under
//     gather); (3) bucket_fill: keep phase-1 records in registers, delete
//     phase-3 ebuf re-read.
//   - Everything else identical to R21.
// ---------------------------------------------------------------------------

#define NEG_SLOPE 0.2f
#define NEG_BIG -3.0e38f

#define BSHIFT 9
#define BSIZE 512            // nodes per bucket
#define CEPB 8192            // edges per chunk block
#define ECAP 112             // ebuf records per (bucket,chunk) slot
#define CBPAD 256            // blockHist row stride

typedef __bf16 bf16x8 __attribute__((ext_vector_type(8)));
typedef __bf16 bf16x4 __attribute__((ext_vector_type(4)));
typedef float f32x4 __attribute__((ext_vector_type(4)));

__device__ __forceinline__ float lrelu(float x) {
    return x >= 0.f ? x : NEG_SLOPE * x;
}

__device__ __forceinline__ int wave_incl_scan(int v, int lane) {
#pragma unroll
    for (int d = 1; d < 64; d <<= 1) {
        int t = __shfl_up(v, d, 64);
        if (lane >= d) v += t;
    }
    return v;
}

// ------- fused: hist+place || gemm1 (K=128, fp32 A hi/lo) || precompute ----

__global__ __launch_bounds__(256) void fused_hist_gemm(
        const int* __restrict__ src, const int* __restrict__ dst,
        int* __restrict__ bucketCount, int* __restrict__ blockHist,
        unsigned* __restrict__ ebuf, int E, int CB,
        const float* __restrict__ X, const float* __restrict__ W,
        const float* __restrict__ a_src, const float* __restrict__ a_dst,
        __bf16* __restrict__ Hout, float* __restrict__ as_, float* __restrict__ ad_,
        int N, int nTiles,
        const float* __restrict__ W2g, const float* __restrict__ Wlg,
        const float* __restrict__ blg, const float* __restrict__ b2g,
        const float* __restrict__ a_src2, const float* __restrict__ a_dst2,
        float* __restrict__ Wc, float* __restrict__ bc,
        float* __restrict__ u2, float* __restrict__ v2) {
    constexpr int K = 128;
    __shared__ __bf16 Whi[64][K + 8];
    __shared__ __bf16 Wlo[64][K + 8];
    __shared__ int hist[256];

    if (blockIdx.x < (unsigned)CB) {
        // ---- hist+place path: LDS rank capture, direct slotted ebuf write --
        const int t = threadIdx.x;
        hist[t] = 0;
        __syncthreads();
        const int c = blockIdx.x;
        const int e0 = c * CEPB;
        const int e1 = min(e0 + CEPB, E);
        int rr[CEPB / 256];
#pragma unroll
        for (int i = 0; i < CEPB / 256; ++i) {
            int e = e0 + i * 256 + t;
            if (e < e1) rr[i] = atomicAdd(&hist[dst[e] >> BSHIFT], 1);
        }
        __syncthreads();
        int hv = hist[t];
        blockHist[t * CBPAD + c] = hv;                    // plain store
        if (hv > 0) atomicAdd(&bucketCount[t], hv);       // fire-and-forget
#pragma unroll
        for (int i = 0; i < CEPB / 256; ++i) {
            int e = e0 + i * 256 + t;
            if (e < e1) {
                int d = dst[e];                            // L1/L2 hot
                int b = d >> BSHIFT;
                ebuf[((size_t)b * CB + c) * ECAP + rr[i]] =
                    ((unsigned)src[e] << BSHIFT) | (unsigned)(d & (BSIZE - 1));
            }
        }
        return;
    }

    if (blockIdx.x == (unsigned)(CB + 1024)) {
        // ---- precompute block (LDS-staged): Wc=W2@Wl, bc=b2@Wl+bl,
        //      u2/v2 = W2@a_*. Reuse Whi/Wlo LDS as float scratch.
        const int t = threadIdx.x;
        float* W2s = (float*)&Whi[0][0];   // 64*64*4 = 16384 B <= 17408 B
        float* Wls = (float*)&Wlo[0][0];   // 64*40*4 = 10240 B <= 17408 B
        for (int idx = t; idx < 64 * 64; idx += 256) W2s[idx] = W2g[idx];
        for (int idx = t; idx < 64 * 40; idx += 256) Wls[idx] = Wlg[idx];
        __syncthreads();
        for (int idx = t; idx < 64 * 40; idx += 256) {
            int k = idx / 40, c = idx - k * 40;
            float s = 0.f;
#pragma unroll 8
            for (int j = 0; j < 64; ++j) s += W2s[k * 64 + j] * Wls[j * 40 + c];
            Wc[idx] = s;
        }
        if (t < 40) {
            float s = blg[t];
            for (int j = 0; j < 64; ++j) s += b2g[j] * Wls[j * 40 + t];
            bc[t] = s;
        }
        if (t >= 64 && t < 128) {
            int r = t - 64;
            float su = 0.f, sv = 0.f;
            for (int j = 0; j < 64; ++j) {
                float w = W2s[r * 64 + j];
                su += w * a_src2[j];
                sv += w * a_dst2[j];
            }
            u2[r] = su;
            v2[r] = sv;
        }
        return;
    }

    // ---- gemm path ----
    const int gbid = blockIdx.x - CB;
    for (int idx = threadIdx.x; idx < K * 64; idx += 256) {
        int k = idx >> 6, n = idx & 63;
        float w = W[idx];
        __bf16 hi = (__bf16)w;
        Whi[n][k] = hi;
        Wlo[n][k] = (__bf16)(w - (float)hi);
    }
    __syncthreads();

    const int lane  = threadIdx.x & 63;
    const int wave  = threadIdx.x >> 6;
    const int row16 = lane & 15;
    const int quad  = lane >> 4;

    float asv[4], adv[4];
#pragma unroll
    for (int t = 0; t < 4; ++t) {
        asv[t] = a_src[t * 16 + row16];
        adv[t] = a_dst[t * 16 + row16];
    }

    for (int tile = gbid; tile < nTiles; tile += 1024) {
        const int nbase = tile * 64;
        int gn = nbase + wave * 16 + row16;
        if (gn >= N) gn = N - 1;
        const float* __restrict__ xp = X + (size_t)gn * K + quad * 8;

        float4 xv[K / 16];
#pragma unroll
        for (int c = 0; c < K / 32; ++c) {
            xv[2 * c]     = *(const float4*)(xp + c * 32);
            xv[2 * c + 1] = *(const float4*)(xp + c * 32 + 4);
        }

        f32x4 acc[4] = {{0.f, 0.f, 0.f, 0.f}, {0.f, 0.f, 0.f, 0.f},
                        {0.f, 0.f, 0.f, 0.f}, {0.f, 0.f, 0.f, 0.f}};
#pragma unroll
        for (int kc = 0; kc < K; kc += 32) {
            float xs[8];
            *(float4*)&xs[0] = xv[kc / 16];
            *(float4*)&xs[4] = xv[kc / 16 + 1];
            bf16x8 ahi, alo;
#pragma unroll
            for (int j = 0; j < 8; ++j) {
                __bf16 hi = (__bf16)xs[j];
                ahi[j] = hi;
                alo[j] = (__bf16)(xs[j] - (float)hi);
            }
#pragma unroll
            for (int t = 0; t < 4; ++t) {
                bf16x8 bhi = *(const bf16x8*)&Whi[t * 16 + row16][kc + quad * 8];
                bf16x8 blo = *(const bf16x8*)&Wlo[t * 16 + row16][kc + quad * 8];
                acc[t] = __builtin_amdgcn_mfma_f32_16x16x32_bf16(ahi, bhi, acc[t], 0, 0, 0);
                acc[t] = __builtin_amdgcn_mfma_f32_16x16x32_bf16(ahi, blo, acc[t], 0, 0, 0);
                acc[t] = __builtin_amdgcn_mfma_f32_16x16x32_bf16(alo, bhi, acc[t], 0, 0, 0);
            }
        }

        float ps[4] = {0.f, 0.f, 0.f, 0.f};
        float pd[4] = {0.f, 0.f, 0.f, 0.f};
#pragma unroll
        for (int t = 0; t < 4; ++t) {
#pragma unroll
            for (int r = 0; r < 4; ++r) {
                int gm = nbase + wave * 16 + quad * 4 + r;
                if (gm < N) Hout[(size_t)gm * 64 + t * 16 + row16] = (__bf16)acc[t][r];
                ps[r] = fmaf(acc[t][r], asv[t], ps[r]);
                pd[r] = fmaf(acc[t][r], adv[t], pd[r]);
            }
        }
#pragma unroll
        for (int r = 0; r < 4; ++r) {
#pragma unroll
            for (int d = 1; d < 16; d <<= 1) {
                ps[r] += __shfl_xor(ps[r], d, 64);
                pd[r] += __shfl_xor(pd[r], d, 64);
            }
        }
        if (row16 == 0) {
#pragma unroll
            for (int r = 0; r < 4; ++r) {
                int gm = nbase + wave * 16 + quad * 4 + r;
                if (gm < N) { as_[gm] = ps[r]; ad_[gm] = pd[r]; }
            }
        }
    }
}

// ---------------- per-bucket: gbase + offs + csr fill (LDS ranks) ----------
// R22: records kept in registers from phase 1; no phase-3 ebuf re-read.

__global__ __launch_bounds__(1024) void bucket_fill(const unsigned* __restrict__ ebuf,
                                                    const int* __restrict__ blockHist,
                                                    const int* __restrict__ bucketCount,
                                                    int* __restrict__ offs,
                                                    int* __restrict__ csr,
                                                    int N, int E, int CB) {
    __shared__ int hist[512], excls[512], bhist_s[256], wsum[16], gsum[16];
    const int b = blockIdx.x;
    const int t = threadIdx.x;       // 0..1023
    const int lane = t & 63;
    const int w = t >> 6;            // 0..15

    // gbase = sum of bucketCount[0..b-1] (waves 0..3 carry data)
    int v = (t < 256 && t < b) ? bucketCount[t] : 0;
#pragma unroll
    for (int d = 32; d; d >>= 1) v += __shfl_xor(v, d, 64);
    if (lane == 0) gsum[w] = v;
    if (t < 512) hist[t] = 0;
    if (t < 256) bhist_s[t] = blockHist[b * CBPAD + t];
    if (b == 0 && t == 0) offs[N] = E;
    __syncthreads();
    int gbase = 0;
#pragma unroll
    for (int i = 0; i < 16; ++i) gbase += gsum[i];

    // phase 1: node-degree histogram with register rank + record capture.
    int rr[32];
    unsigned recs[32];
#pragma unroll
    for (int ci = 0; ci < 16; ++ci) {
        int c = w + ci * 16;
        int cnt = (c < CB) ? bhist_s[c] : 0;
        const unsigned* __restrict__ ep = ebuf + ((size_t)b * CB + c) * ECAP;
#pragma unroll
        for (int ri = 0; ri < 2; ++ri) {
            int idx = ri * 64 + lane;
            if (idx < cnt) {
                unsigned rec = ep[idx];
                recs[ci * 2 + ri] = rec;
                rr[ci * 2 + ri] = atomicAdd(&hist[rec & (BSIZE - 1)], 1);
            }
        }
    }
    __syncthreads();

    // phase 2: 512-entry exclusive scan (waves 0..7) -> offs
    int hv = (t < 512) ? hist[t] : 0;
    int incl = wave_incl_scan(hv, lane);
    if (lane == 63 && w < 8) wsum[w] = incl;
    __syncthreads();
    if (t < 512) {
        int pre = 0;
#pragma unroll
        for (int i = 0; i < 8; ++i) pre += (i < w) ? wsum[i] : 0;
        int excl = incl - hv + pre;
        int n = b * BSIZE + t;
        if (n < N) offs[n] = gbase + excl;
        excls[t] = excl;
    }
    __syncthreads();

    // phase 3: write csr from registers (no ebuf re-read)
#pragma unroll
    for (int ci = 0; ci < 16; ++ci) {
        int c = w + ci * 16;
        int cnt = (c < CB) ? bhist_s[c] : 0;
#pragma unroll
        for (int ri = 0; ri < 2; ++ri) {
            int idx = ri * 64 + lane;
            if (idx < cnt) {
                unsigned rec = recs[ci * 2 + ri];
                csr[gbase + excls[rec & (BSIZE - 1)] + rr[ci * 2 + ri]] =
                    (int)(rec >> BSHIFT);
            }
        }
    }
}

// ------------- fused segment softmax + aggregation (4x16, 8-deep MLP) ------
// Optional epilogue (u2 != nullptr): as_out/ad_out = x2row . u2/v2
// R22: u4/v4/b4 loaded at entry (latency hidden under gather loop).

__global__ __launch_bounds__(256) void gat_agg(const __bf16* __restrict__ h,
                                               const float* __restrict__ as_,
                                               const float* __restrict__ ad_,
                                               const float* __restrict__ bias,
                                               const int* __restrict__ offs,
                                               const int* __restrict__ csr,
                                               __bf16* __restrict__ out,
                                               int N, int do_relu,
                                               const float* __restrict__ u2,
                                               const float* __restrict__ v2,
                                               float* __restrict__ as_out,
                                               float* __restrict__ ad_out) {
    int gtid = blockIdx.x * blockDim.x + threadIdx.x;
    int n = __builtin_amdgcn_readfirstlane(gtid >> 6);
    if (n >= N) return;
    const int lane = threadIdx.x & 63;
    const int g  = lane >> 4;   // edge group 0..3
    const int fl = lane & 15;   // feature quad index

    // hoisted constant loads (hide latency under the gather loop)
    const float4 b4 = *(const float4*)(bias + fl * 4);
    float4 u4 = {0.f, 0.f, 0.f, 0.f}, v4 = {0.f, 0.f, 0.f, 0.f};
    if (u2 != nullptr) {
        u4 = *(const float4*)(u2 + fl * 4);
        v4 = *(const float4*)(v2 + fl * 4);
    }

    int beg = offs[n], end = offs[n + 1];
    float adn = ad_[n];
    float p_self = __expf(lrelu(as_[n] + adn));

    float den = p_self;
    float ax, ay, az, aw;
    {
        bf16x4 t = *(const bf16x4*)(h + (size_t)n * 64 + fl * 4);
        float m0 = (g == 0) ? p_self : 0.f;
        ax = m0 * (float)t[0];
        ay = m0 * (float)t[1];
        az = m0 * (float)t[2];
        aw = m0 * (float)t[3];
    }

    for (int c0 = beg; c0 < end; c0 += 64) {
        int cnt = end - c0;
        if (cnt > 64) cnt = 64;
        int   s_l = (lane < cnt) ? csr[c0 + lane] : 0;
        float p_l = (lane < cnt) ? __expf(lrelu(as_[s_l] + adn)) : 0.f;
        float csum = p_l;
#pragma unroll
        for (int d = 32; d; d >>= 1) csum += __shfl_xor(csum, d, 64);
        den += csum;

        // 8 independent gathers in flight per iteration (32 edges).
        int rounds = (cnt + 3) >> 2;
        for (int r = 0; r < rounds; r += 8) {
            int s[8];
#pragma unroll
            for (int i = 0; i < 8; ++i) s[i] = __shfl(s_l, (r + i) * 4 + g, 64);
            bf16x4 hv[8];
#pragma unroll
            for (int i = 0; i < 8; ++i)
                hv[i] = *(const bf16x4*)(h + (size_t)s[i] * 64 + fl * 4);
            float w[8];
#pragma unroll
            for (int i = 0; i < 8; ++i) w[i] = __shfl(p_l, (r + i) * 4 + g, 64);
#pragma unroll
            for (int i = 0; i < 8; ++i) {
                ax = fmaf(w[i], (float)hv[i][0], ax);
                ay = fmaf(w[i], (float)hv[i][1], ay);
                az = fmaf(w[i], (float)hv[i][2], az);
                aw = fmaf(w[i], (float)hv[i][3], aw);
            }
        }
    }

#pragma unroll
    for (int d = 16; d <= 32; d <<= 1) {
        ax += __shfl_xor(ax, d, 64);
        ay += __shfl_xor(ay, d, 64);
        az += __shfl_xor(az, d, 64);
        aw += __shfl_xor(aw, d, 64);
    }
    if (g == 0) {
        float inv = 1.f / (den + 1e-16f);
        float o0 = fmaf(ax, inv, b4.x);
        float o1 = fmaf(ay, inv, b4.y);
        float o2 = fmaf(az, inv, b4.z);
        float o3 = fmaf(aw, inv, b4.w);
        if (do_relu) {
            o0 = fmaxf(o0, 0.f); o1 = fmaxf(o1, 0.f);
            o2 = fmaxf(o2, 0.f); o3 = fmaxf(o3, 0.f);
        }
        bf16x4 ov;
        ov[0] = (__bf16)o0; ov[1] = (__bf16)o1;
        ov[2] = (__bf16)o2; ov[3] = (__bf16)o3;
        *(bf16x4*)(out + (size_t)n * 64 + fl * 4) = ov;

        if (u2 != nullptr) {
            float pu = o0 * u4.x + o1 * u4.y + o2 * u4.z + o3 * u4.w;
            float pv = o0 * v4.x + o1 * v4.y + o2 * v4.z + o3 * v4.w;
#pragma unroll
            for (int d = 1; d <= 8; d <<= 1) {
                pu += __shfl_xor(pu, d, 64);
                pv += __shfl_xor(pv, d, 64);
            }
            if (fl == 0) { as_out[n] = pu; ad_out[n] = pv; }
        }
    }
}

// ---------------- final linear (y@Wc + bc, 2-term) + log_softmax -----------
// R22: coalesced linear Wl staging (was 160B-strided uncoalesced).

__global__ __launch_bounds__(256) void final_lsm(const __bf16* __restrict__ h,
                                                 const float* __restrict__ Wl,
                                                 const float* __restrict__ bl,
                                                 float* __restrict__ out,
                                                 int N, int nTiles) {
    __shared__ __bf16 Whi[48][72];
    __shared__ __bf16 Wlo[48][72];
    __shared__ float bls[48];
    // coalesced read of Wl (k-major), transpose on the LDS write
    for (int idx = threadIdx.x; idx < 64 * 40; idx += 256) {
        int k = idx / 40, c = idx - k * 40;
        float w = Wl[idx];
        __bf16 hi = (__bf16)w;
        Whi[c][k] = hi;
        Wlo[c][k] = (__bf16)(w - (float)hi);
    }
    // zero-fill pad rows c = 40..47
    for (int idx = threadIdx.x; idx < 8 * 64; idx += 256) {
        int c = 40 + (idx >> 6), k = idx & 63;
        Whi[c][k] = (__bf16)0.f;
        Wlo[c][k] = (__bf16)0.f;
    }
    if (threadIdx.x < 48) bls[threadIdx.x] = (threadIdx.x < 40) ? bl[threadIdx.x] : 0.f;
    __syncthreads();

    const int lane  = threadIdx.x & 63;
    const int wave  = threadIdx.x >> 6;
    const int col16 = lane & 15;
    const int quad  = lane >> 4;

    for (int tile = blockIdx.x; tile < nTiles; tile += gridDim.x) {
        const int nbase = tile * 64;
        int gn = nbase + wave * 16 + col16;
        if (gn >= N) gn = N - 1;
        const __bf16* __restrict__ xp = h + (size_t)gn * 64 + quad * 8;
        bf16x8 a0 = *(const bf16x8*)(xp);
        bf16x8 a1 = *(const bf16x8*)(xp + 32);

        f32x4 acc[3] = {{0.f, 0.f, 0.f, 0.f}, {0.f, 0.f, 0.f, 0.f},
                        {0.f, 0.f, 0.f, 0.f}};
#pragma unroll
        for (int kc = 0; kc < 64; kc += 32) {
            bf16x8 a = (kc == 0) ? a0 : a1;
#pragma unroll
            for (int t = 0; t < 3; ++t) {
                bf16x8 bhi = *(const bf16x8*)&Whi[t * 16 + col16][kc + quad * 8];
                bf16x8 blo = *(const bf16x8*)&Wlo[t * 16 + col16][kc + quad * 8];
                acc[t] = __builtin_amdgcn_mfma_f32_16x16x32_bf16(a, bhi, acc[t], 0, 0, 0);
                acc[t] = __builtin_amdgcn_mfma_f32_16x16x32_bf16(a, blo, acc[t], 0, 0, 0);
            }
        }

#pragma unroll
        for (int r = 0; r < 4; ++r) {
            int gm = nbase + wave * 16 + quad * 4 + r;
            float l0 = acc[0][r] + bls[col16];
            float l1 = acc[1][r] + bls[16 + col16];
            float l2 = (col16 < 8) ? (acc[2][r] + bls[32 + col16]) : NEG_BIG;
            float mx = fmaxf(fmaxf(l0, l1), l2);
#pragma unroll
            for (int d = 1; d < 16; d <<= 1) mx = fmaxf(mx, __shfl_xor(mx, d, 64));
            float s = __expf(l0 - mx) + __expf(l1 - mx) +
                      ((col16 < 8) ? __expf(l2 - mx) : 0.f);
#pragma unroll
            for (int d = 1; d < 16; d <<= 1) s += __shfl_xor(s, d, 64);
            float lse = mx + __logf(s);
            if (gm < N) {
                out[(size_t)gm * 40 + col16]      = l0 - lse;
                out[(size_t)gm * 40 + 16 + col16] = l1 - lse;
                if (col16 < 8) out[(size_t)gm * 40 + 32 + col16] = l2 - lse;
            }
        }
    }
}

// ---------------- launch ----------------

extern "C" void kernel_launch(void* const* d_in, const int* in_sizes, int n_in,
                              void* d_out, int out_size, void* d_ws, size_t ws_size,
                              hipStream_t stream) {
    const float* x      = (const float*)d_in[0];
    const int*   ei     = (const int*)d_in[1];
    const float* W1     = (const float*)d_in[2];
    const float* a_src1 = (const float*)d_in[3];
    const float* a_dst1 = (const float*)d_in[4];
    const float* b1     = (const float*)d_in[5];
    const float* W2     = (const float*)d_in[6];
    const float* a_src2 = (const float*)d_in[7];
    const float* a_dst2 = (const float*)d_in[8];
    const float* b2     = (const float*)d_in[9];
    const float* Wl     = (const float*)d_in[10];
    const float* bl     = (const float*)d_in[11];

    const int N = in_sizes[0] / 128;
    const int E = in_sizes[1] / 2;
    const int* src = ei;
    const int* dst = ei + E;
    const int nbuck = (N + BSIZE - 1) >> BSHIFT;
    const int CB = (E + CEPB - 1) / CEPB;   // must be <= 256

    char* p = (char*)d_ws;
    auto alloc = [&](size_t bytes) -> void* {
        void* r = (void*)p;
        p += (bytes + 255) & ~(size_t)255;
        return r;
    };
    int*      offs        = (int*)alloc((size_t)(N + 1) * 4);
    int*      bucketCount = (int*)alloc(256 * 4);
    float*    zbias       = (float*)alloc(64 * 4);        // zeroed with bucketCount
    int*      blockHist   = (int*)alloc(256 * CBPAD * 4);
    unsigned* ebuf        = (unsigned*)alloc((size_t)nbuck * CB * ECAP * 4);
    int*      csr         = (int*)alloc((size_t)E * 4);
    __bf16*   hbf         = (__bf16*)alloc((size_t)N * 64 * 2);  // h1, then y
    __bf16*   habg        = (__bf16*)alloc((size_t)N * 64 * 2);  // x2 = agg1 out
    float*    as_         = (float*)alloc((size_t)N * 4);
    float*    ad_         = (float*)alloc((size_t)N * 4);
    float*    as2_        = (float*)alloc((size_t)N * 4);
    float*    ad2_        = (float*)alloc((size_t)N * 4);
    float*    Wc          = (float*)alloc(64 * 40 * 4);
    float*    bc          = (float*)alloc(40 * 4);
    float*    u2          = (float*)alloc(64 * 4);
    float*    v2          = (float*)alloc(64 * 4);

    // bucketCount (1024B) and zbias (256B) are adjacent -> one memset
    hipMemsetAsync(bucketCount, 0, 1024 + 256, stream);

    const int nTiles = (N + 63) / 64;
    int aggBlocks = (N * 64 + 255) / 256;

    fused_hist_gemm<<<CB + 1025, 256, 0, stream>>>(
        src, dst, bucketCount, blockHist, ebuf, E, CB,
        x, W1, a_src1, a_dst1, hbf, as_, ad_, N, nTiles,
        W2, Wl, bl, b2, a_src2, a_dst2, Wc, bc, u2, v2);
    bucket_fill<<<nbuck, 1024, 0, stream>>>(ebuf, blockHist, bucketCount,
                                            offs, csr, N, E, CB);
    gat_agg<<<aggBlocks, 256, 0, stream>>>(hbf, as_, ad_, b1, offs, csr, habg,
                                           N, 1, u2, v2, as2_, ad2_);
    gat_agg<<<aggBlocks, 256, 0, stream>>>(habg, as2_, ad2_, zbias, offs, csr, hbf,
                                           N, 0, nullptr, nullptr, nullptr, nullptr);
    final_lsm<<<nTiles, 256, 0, stream>>>(hbf, Wc, bc, (float*)d_out, N, nTiles);
}

// Round 12
// 269.170 us; speedup vs baseline: 1.2421x; 1.0022x over previous
//
#include <hip/hip_runtime.h>
#include <math.h>

// ---------------------------------------------------------------------------
// GAT x2 + linear + log_softmax on MI355X. R23.
//   - R22 post-mortem (269.8 best): ~110us hides in never-top-5 kernels.
//     final_lsm = 1563 blocks x {stage 10KB Wl -> compute ONE tile}: ~15:1
//     staging:compute waste. fused gemm path: 539 of 1024 blocks serially
//     run 2 tiles (kernel tail = 2x tile).
//   - R23: (1) final_lsm <<<512>>> grid-stride (~3 tiles/block, staging
//     amortized, staging/compute overlap across blocks); (2) fused gemm:
//     exactly 1 tile/block (grid = CB+1+nTiles, precompute block at slot CB).
//     Numerics bitwise-identical per tile.
//   - Everything else identical to R22.
// ---------------------------------------------------------------------------

#define NEG_SLOPE 0.2f
#define NEG_BIG -3.0e38f

#define BSHIFT 9
#define BSIZE 512            // nodes per bucket
#define CEPB 8192            // edges per chunk block
#define ECAP 112             // ebuf records per (bucket,chunk) slot
#define CBPAD 256            // blockHist row stride

typedef __bf16 bf16x8 __attribute__((ext_vector_type(8)));
typedef __bf16 bf16x4 __attribute__((ext_vector_type(4)));
typedef float f32x4 __attribute__((ext_vector_type(4)));

__device__ __forceinline__ float lrelu(float x) {
    return x >= 0.f ? x : NEG_SLOPE * x;
}

__device__ __forceinline__ int wave_incl_scan(int v, int lane) {
#pragma unroll
    for (int d = 1; d < 64; d <<= 1) {
        int t = __shfl_up(v, d, 64);
        if (lane >= d) v += t;
    }
    return v;
}

// ------- fused: hist+place || precompute || gemm1 (1 tile/block) -----------

__global__ __launch_bounds__(256) void fused_hist_gemm(
        const int* __restrict__ src, const int* __restrict__ dst,
        int* __restrict__ bucketCount, int* __restrict__ blockHist,
        unsigned* __restrict__ ebuf, int E, int CB,
        const float* __restrict__ X, const float* __restrict__ W,
        const float* __restrict__ a_src, const float* __restrict__ a_dst,
        __bf16* __restrict__ Hout, float* __restrict__ as_, float* __restrict__ ad_,
        int N, int nTiles,
        const float* __restrict__ W2g, const float* __restrict__ Wlg,
        const float* __restrict__ blg, const float* __restrict__ b2g,
        const float* __restrict__ a_src2, const float* __restrict__ a_dst2,
        float* __restrict__ Wc, float* __restrict__ bc,
        float* __restrict__ u2, float* __restrict__ v2) {
    constexpr int K = 128;
    __shared__ __bf16 Whi[64][K + 8];
    __shared__ __bf16 Wlo[64][K + 8];
    __shared__ int hist[256];

    if (blockIdx.x < (unsigned)CB) {
        // ---- hist+place path: LDS rank capture, direct slotted ebuf write --
        const int t = threadIdx.x;
        hist[t] = 0;
        __syncthreads();
        const int c = blockIdx.x;
        const int e0 = c * CEPB;
        const int e1 = min(e0 + CEPB, E);
        int rr[CEPB / 256];
#pragma unroll
        for (int i = 0; i < CEPB / 256; ++i) {
            int e = e0 + i * 256 + t;
            if (e < e1) rr[i] = atomicAdd(&hist[dst[e] >> BSHIFT], 1);
        }
        __syncthreads();
        int hv = hist[t];
        blockHist[t * CBPAD + c] = hv;                    // plain store
        if (hv > 0) atomicAdd(&bucketCount[t], hv);       // fire-and-forget
#pragma unroll
        for (int i = 0; i < CEPB / 256; ++i) {
            int e = e0 + i * 256 + t;
            if (e < e1) {
                int d = dst[e];                            // L1/L2 hot
                int b = d >> BSHIFT;
                ebuf[((size_t)b * CB + c) * ECAP + rr[i]] =
                    ((unsigned)src[e] << BSHIFT) | (unsigned)(d & (BSIZE - 1));
            }
        }
        return;
    }

    if (blockIdx.x == (unsigned)CB) {
        // ---- precompute block (LDS-staged): Wc=W2@Wl, bc=b2@Wl+bl,
        //      u2/v2 = W2@a_*. Reuse Whi/Wlo LDS as float scratch.
        const int t = threadIdx.x;
        float* W2s = (float*)&Whi[0][0];   // 64*64*4 = 16384 B <= 17408 B
        float* Wls = (float*)&Wlo[0][0];   // 64*40*4 = 10240 B <= 17408 B
        for (int idx = t; idx < 64 * 64; idx += 256) W2s[idx] = W2g[idx];
        for (int idx = t; idx < 64 * 40; idx += 256) Wls[idx] = Wlg[idx];
        __syncthreads();
        for (int idx = t; idx < 64 * 40; idx += 256) {
            int k = idx / 40, c = idx - k * 40;
            float s = 0.f;
#pragma unroll 8
            for (int j = 0; j < 64; ++j) s += W2s[k * 64 + j] * Wls[j * 40 + c];
            Wc[idx] = s;
        }
        if (t < 40) {
            float s = blg[t];
            for (int j = 0; j < 64; ++j) s += b2g[j] * Wls[j * 40 + t];
            bc[t] = s;
        }
        if (t >= 64 && t < 128) {
            int r = t - 64;
            float su = 0.f, sv = 0.f;
            for (int j = 0; j < 64; ++j) {
                float w = W2s[r * 64 + j];
                su += w * a_src2[j];
                sv += w * a_dst2[j];
            }
            u2[r] = su;
            v2[r] = sv;
        }
        return;
    }

    // ---- gemm path: exactly one tile per block ----
    const int tile = blockIdx.x - CB - 1;
    if (tile >= nTiles) return;
    for (int idx = threadIdx.x; idx < K * 64; idx += 256) {
        int k = idx >> 6, n = idx & 63;
        float w = W[idx];
        __bf16 hi = (__bf16)w;
        Whi[n][k] = hi;
        Wlo[n][k] = (__bf16)(w - (float)hi);
    }
    __syncthreads();

    const int lane  = threadIdx.x & 63;
    const int wave  = threadIdx.x >> 6;
    const int row16 = lane & 15;
    const int quad  = lane >> 4;

    float asv[4], adv[4];
#pragma unroll
    for (int t = 0; t < 4; ++t) {
        asv[t] = a_src[t * 16 + row16];
        adv[t] = a_dst[t * 16 + row16];
    }

    {
        const int nbase = tile * 64;
        int gn = nbase + wave * 16 + row16;
        if (gn >= N) gn = N - 1;
        const float* __restrict__ xp = X + (size_t)gn * K + quad * 8;

        float4 xv[K / 16];
#pragma unroll
        for (int c = 0; c < K / 32; ++c) {
            xv[2 * c]     = *(const float4*)(xp + c * 32);
            xv[2 * c + 1] = *(const float4*)(xp + c * 32 + 4);
        }

        f32x4 acc[4] = {{0.f, 0.f, 0.f, 0.f}, {0.f, 0.f, 0.f, 0.f},
                        {0.f, 0.f, 0.f, 0.f}, {0.f, 0.f, 0.f, 0.f}};
#pragma unroll
        for (int kc = 0; kc < K; kc += 32) {
            float xs[8];
            *(float4*)&xs[0] = xv[kc / 16];
            *(float4*)&xs[4] = xv[kc / 16 + 1];
            bf16x8 ahi, alo;
#pragma unroll
            for (int j = 0; j < 8; ++j) {
                __bf16 hi = (__bf16)xs[j];
                ahi[j] = hi;
                alo[j] = (__bf16)(xs[j] - (float)hi);
            }
#pragma unroll
            for (int t = 0; t < 4; ++t) {
                bf16x8 bhi = *(const bf16x8*)&Whi[t * 16 + row16][kc + quad * 8];
                bf16x8 blo = *(const bf16x8*)&Wlo[t * 16 + row16][kc + quad * 8];
                acc[t] = __builtin_amdgcn_mfma_f32_16x16x32_bf16(ahi, bhi, acc[t], 0, 0, 0);
                acc[t] = __builtin_amdgcn_mfma_f32_16x16x32_bf16(ahi, blo, acc[t], 0, 0, 0);
                acc[t] = __builtin_amdgcn_mfma_f32_16x16x32_bf16(alo, bhi, acc[t], 0, 0, 0);
            }
        }

        float ps[4] = {0.f, 0.f, 0.f, 0.f};
        float pd[4] = {0.f, 0.f, 0.f, 0.f};
#pragma unroll
        for (int t = 0; t < 4; ++t) {
#pragma unroll
            for (int r = 0; r < 4; ++r) {
                int gm = nbase + wave * 16 + quad * 4 + r;
                if (gm < N) Hout[(size_t)gm * 64 + t * 16 + row16] = (__bf16)acc[t][r];
                ps[r] = fmaf(acc[t][r], asv[t], ps[r]);
                pd[r] = fmaf(acc[t][r], adv[t], pd[r]);
            }
        }
#pragma unroll
        for (int r = 0; r < 4; ++r) {
#pragma unroll
            for (int d = 1; d < 16; d <<= 1) {
                ps[r] += __shfl_xor(ps[r], d, 64);
                pd[r] += __shfl_xor(pd[r], d, 64);
            }
        }
        if (row16 == 0) {
#pragma unroll
            for (int r = 0; r < 4; ++r) {
                int gm = nbase + wave * 16 + quad * 4 + r;
                if (gm < N) { as_[gm] = ps[r]; ad_[gm] = pd[r]; }
            }
        }
    }
}

// ---------------- per-bucket: gbase + offs + csr fill (LDS ranks) ----------
// Records kept in registers from phase 1; no phase-3 ebuf re-read.

__global__ __launch_bounds__(1024) void bucket_fill(const unsigned* __restrict__ ebuf,
                                                    const int* __restrict__ blockHist,
                                                    const int* __restrict__ bucketCount,
                                                    int* __restrict__ offs,
                                                    int* __restrict__ csr,
                                                    int N, int E, int CB) {
    __shared__ int hist[512], excls[512], bhist_s[256], wsum[16], gsum[16];
    const int b = blockIdx.x;
    const int t = threadIdx.x;       // 0..1023
    const int lane = t & 63;
    const int w = t >> 6;            // 0..15

    // gbase = sum of bucketCount[0..b-1] (waves 0..3 carry data)
    int v = (t < 256 && t < b) ? bucketCount[t] : 0;
#pragma unroll
    for (int d = 32; d; d >>= 1) v += __shfl_xor(v, d, 64);
    if (lane == 0) gsum[w] = v;
    if (t < 512) hist[t] = 0;
    if (t < 256) bhist_s[t] = blockHist[b * CBPAD + t];
    if (b == 0 && t == 0) offs[N] = E;
    __syncthreads();
    int gbase = 0;
#pragma unroll
    for (int i = 0; i < 16; ++i) gbase += gsum[i];

    // phase 1: node-degree histogram with register rank + record capture.
    int rr[32];
    unsigned recs[32];
#pragma unroll
    for (int ci = 0; ci < 16; ++ci) {
        int c = w + ci * 16;
        int cnt = (c < CB) ? bhist_s[c] : 0;
        const unsigned* __restrict__ ep = ebuf + ((size_t)b * CB + c) * ECAP;
#pragma unroll
        for (int ri = 0; ri < 2; ++ri) {
            int idx = ri * 64 + lane;
            if (idx < cnt) {
                unsigned rec = ep[idx];
                recs[ci * 2 + ri] = rec;
                rr[ci * 2 + ri] = atomicAdd(&hist[rec & (BSIZE - 1)], 1);
            }
        }
    }
    __syncthreads();

    // phase 2: 512-entry exclusive scan (waves 0..7) -> offs
    int hv = (t < 512) ? hist[t] : 0;
    int incl = wave_incl_scan(hv, lane);
    if (lane == 63 && w < 8) wsum[w] = incl;
    __syncthreads();
    if (t < 512) {
        int pre = 0;
#pragma unroll
        for (int i = 0; i < 8; ++i) pre += (i < w) ? wsum[i] : 0;
        int excl = incl - hv + pre;
        int n = b * BSIZE + t;
        if (n < N) offs[n] = gbase + excl;
        excls[t] = excl;
    }
    __syncthreads();

    // phase 3: write csr from registers (no ebuf re-read)
#pragma unroll
    for (int ci = 0; ci < 16; ++ci) {
        int c = w + ci * 16;
        int cnt = (c < CB) ? bhist_s[c] : 0;
#pragma unroll
        for (int ri = 0; ri < 2; ++ri) {
            int idx = ri * 64 + lane;
            if (idx < cnt) {
                unsigned rec = recs[ci * 2 + ri];
                csr[gbase + excls[rec & (BSIZE - 1)] + rr[ci * 2 + ri]] =
                    (int)(rec >> BSHIFT);
            }
        }
    }
}

// ------------- fused segment softmax + aggregation (4x16, 8-deep MLP) ------
// Optional epilogue (u2 != nullptr): as_out/ad_out = x2row . u2/v2

__global__ __launch_bounds__(256) void gat_agg(const __bf16* __restrict__ h,
                                               const float* __restrict__ as_,
                                               const float* __restrict__ ad_,
                                               const float* __restrict__ bias,
                                               const int* __restrict__ offs,
                                               const int* __restrict__ csr,
                                               __bf16* __restrict__ out,
                                               int N, int do_relu,
                                               const float* __restrict__ u2,
                                               const float* __restrict__ v2,
                                               float* __restrict__ as_out,
                                               float* __restrict__ ad_out) {
    int gtid = blockIdx.x * blockDim.x + threadIdx.x;
    int n = __builtin_amdgcn_readfirstlane(gtid >> 6);
    if (n >= N) return;
    const int lane = threadIdx.x & 63;
    const int g  = lane >> 4;   // edge group 0..3
    const int fl = lane & 15;   // feature quad index

    // hoisted constant loads (hide latency under the gather loop)
    const float4 b4 = *(const float4*)(bias + fl * 4);
    float4 u4 = {0.f, 0.f, 0.f, 0.f}, v4 = {0.f, 0.f, 0.f, 0.f};
    if (u2 != nullptr) {
        u4 = *(const float4*)(u2 + fl * 4);
        v4 = *(const float4*)(v2 + fl * 4);
    }

    int beg = offs[n], end = offs[n + 1];
    float adn = ad_[n];
    float p_self = __expf(lrelu(as_[n] + adn));

    float den = p_self;
    float ax, ay, az, aw;
    {
        bf16x4 t = *(const bf16x4*)(h + (size_t)n * 64 + fl * 4);
        float m0 = (g == 0) ? p_self : 0.f;
        ax = m0 * (float)t[0];
        ay = m0 * (float)t[1];
        az = m0 * (float)t[2];
        aw = m0 * (float)t[3];
    }

    for (int c0 = beg; c0 < end; c0 += 64) {
        int cnt = end - c0;
        if (cnt > 64) cnt = 64;
        int   s_l = (lane < cnt) ? csr[c0 + lane] : 0;
        float p_l = (lane < cnt) ? __expf(lrelu(as_[s_l] + adn)) : 0.f;
        float csum = p_l;
#pragma unroll
        for (int d = 32; d; d >>= 1) csum += __shfl_xor(csum, d, 64);
        den += csum;

        // 8 independent gathers in flight per iteration (32 edges).
        int rounds = (cnt + 3) >> 2;
        for (int r = 0; r < rounds; r += 8) {
            int s[8];
#pragma unroll
            for (int i = 0; i < 8; ++i) s[i] = __shfl(s_l, (r + i) * 4 + g, 64);
            bf16x4 hv[8];
#pragma unroll
            for (int i = 0; i < 8; ++i)
                hv[i] = *(const bf16x4*)(h + (size_t)s[i] * 64 + fl * 4);
            float w[8];
#pragma unroll
            for (int i = 0; i < 8; ++i) w[i] = __shfl(p_l, (r + i) * 4 + g, 64);
#pragma unroll
            for (int i = 0; i < 8; ++i) {
                ax = fmaf(w[i], (float)hv[i][0], ax);
                ay = fmaf(w[i], (float)hv[i][1], ay);
                az = fmaf(w[i], (float)hv[i][2], az);
                aw = fmaf(w[i], (float)hv[i][3], aw);
            }
        }
    }

#pragma unroll
    for (int d = 16; d <= 32; d <<= 1) {
        ax += __shfl_xor(ax, d, 64);
        ay += __shfl_xor(ay, d, 64);
        az += __shfl_xor(az, d, 64);
        aw += __shfl_xor(aw, d, 64);
    }
    if (g == 0) {
        float inv = 1.f / (den + 1e-16f);
        float o0 = fmaf(ax, inv, b4.x);
        float o1 = fmaf(ay, inv, b4.y);
        float o2 = fmaf(az, inv, b4.z);
        float o3 = fmaf(aw, inv, b4.w);
        if (do_relu) {
            o0 = fmaxf(o0, 0.f); o1 = fmaxf(o1, 0.f);
            o2 = fmaxf(o2, 0.f); o3 = fmaxf(o3, 0.f);
        }
        bf16x4 ov;
        ov[0] = (__bf16)o0; ov[1] = (__bf16)o1;
        ov[2] = (__bf16)o2; ov[3] = (__bf16)o3;
        *(bf16x4*)(out + (size_t)n * 64 + fl * 4) = ov;

        if (u2 != nullptr) {
            float pu = o0 * u4.x + o1 * u4.y + o2 * u4.z + o3 * u4.w;
            float pv = o0 * v4.x + o1 * v4.y + o2 * v4.z + o3 * v4.w;
#pragma unroll
            for (int d = 1; d <= 8; d <<= 1) {
                pu += __shfl_xor(pu, d, 64);
                pv += __shfl_xor(pv, d, 64);
            }
            if (fl == 0) { as_out[n] = pu; ad_out[n] = pv; }
        }
    }
}

// ---------------- final linear (y@Wc + bc, 2-term) + log_softmax -----------
// R23: 512-block grid-stride (~3 tiles/block) amortizes Wl staging.

__global__ __launch_bounds__(256) void final_lsm(const __bf16* __restrict__ h,
                                                 const float* __restrict__ Wl,
                                                 const float* __restrict__ bl,
                                                 float* __restrict__ out,
                                                 int N, int nTiles) {
    __shared__ __bf16 Whi[48][72];
    __shared__ __bf16 Wlo[48][72];
    __shared__ float bls[48];
    // coalesced read of Wl (k-major), transpose on the LDS write
    for (int idx = threadIdx.x; idx < 64 * 40; idx += 256) {
        int k = idx / 40, c = idx - k * 40;
        float w = Wl[idx];
        __bf16 hi = (__bf16)w;
        Whi[c][k] = hi;
        Wlo[c][k] = (__bf16)(w - (float)hi);
    }
    // zero-fill pad rows c = 40..47
    for (int idx = threadIdx.x; idx < 8 * 64; idx += 256) {
        int c = 40 + (idx >> 6), k = idx & 63;
        Whi[c][k] = (__bf16)0.f;
        Wlo[c][k] = (__bf16)0.f;
    }
    if (threadIdx.x < 48) bls[threadIdx.x] = (threadIdx.x < 40) ? bl[threadIdx.x] : 0.f;
    __syncthreads();

    const int lane  = threadIdx.x & 63;
    const int wave  = threadIdx.x >> 6;
    const int col16 = lane & 15;
    const int quad  = lane >> 4;

    for (int tile = blockIdx.x; tile < nTiles; tile += gridDim.x) {
        const int nbase = tile * 64;
        int gn = nbase + wave * 16 + col16;
        if (gn >= N) gn = N - 1;
        const __bf16* __restrict__ xp = h + (size_t)gn * 64 + quad * 8;
        bf16x8 a0 = *(const bf16x8*)(xp);
        bf16x8 a1 = *(const bf16x8*)(xp + 32);

        f32x4 acc[3] = {{0.f, 0.f, 0.f, 0.f}, {0.f, 0.f, 0.f, 0.f},
                        {0.f, 0.f, 0.f, 0.f}};
#pragma unroll
        for (int kc = 0; kc < 64; kc += 32) {
            bf16x8 a = (kc == 0) ? a0 : a1;
#pragma unroll
            for (int t = 0; t < 3; ++t) {
                bf16x8 bhi = *(const bf16x8*)&Whi[t * 16 + col16][kc + quad * 8];
                bf16x8 blo = *(const bf16x8*)&Wlo[t * 16 + col16][kc + quad * 8];
                acc[t] = __builtin_amdgcn_mfma_f32_16x16x32_bf16(a, bhi, acc[t], 0, 0, 0);
                acc[t] = __builtin_amdgcn_mfma_f32_16x16x32_bf16(a, blo, acc[t], 0, 0, 0);
            }
        }

#pragma unroll
        for (int r = 0; r < 4; ++r) {
            int gm = nbase + wave * 16 + quad * 4 + r;
            float l0 = acc[0][r] + bls[col16];
            float l1 = acc[1][r] + bls[16 + col16];
            float l2 = (col16 < 8) ? (acc[2][r] + bls[32 + col16]) : NEG_BIG;
            float mx = fmaxf(fmaxf(l0, l1), l2);
#pragma unroll
            for (int d = 1; d < 16; d <<= 1) mx = fmaxf(mx, __shfl_xor(mx, d, 64));
            float s = __expf(l0 - mx) + __expf(l1 - mx) +
                      ((col16 < 8) ? __expf(l2 - mx) : 0.f);
#pragma unroll
            for (int d = 1; d < 16; d <<= 1) s += __shfl_xor(s, d, 64);
            float lse = mx + __logf(s);
            if (gm < N) {
                out[(size_t)gm * 40 + col16]      = l0 - lse;
                out[(size_t)gm * 40 + 16 + col16] = l1 - lse;
                if (col16 < 8) out[(size_t)gm * 40 + 32 + col16] = l2 - lse;
            }
        }
    }
}

// ---------------- launch ----------------

extern "C" void kernel_launch(void* const* d_in, const int* in_sizes, int n_in,
                              void* d_out, int out_size, void* d_ws, size_t ws_size,
                              hipStream_t stream) {
    const float* x      = (const float*)d_in[0];
    const int*   ei     = (const int*)d_in[1];
    const float* W1     = (const float*)d_in[2];
    const float* a_src1 = (const float*)d_in[3];
    const float* a_dst1 = (const float*)d_in[4];
    const float* b1     = (const float*)d_in[5];
    const float* W2     = (const float*)d_in[6];
    const float* a_src2 = (const float*)d_in[7];
    const float* a_dst2 = (const float*)d_in[8];
    const float* b2     = (const float*)d_in[9];
    const float* Wl     = (const float*)d_in[10];
    const float* bl     = (const float*)d_in[11];

    const int N = in_sizes[0] / 128;
    const int E = in_sizes[1] / 2;
    const int* src = ei;
    const int* dst = ei + E;
    const int nbuck = (N + BSIZE - 1) >> BSHIFT;
    const int CB = (E + CEPB - 1) / CEPB;   // must be <= 256

    char* p = (char*)d_ws;
    auto alloc = [&](size_t bytes) -> void* {
        void* r = (void*)p;
        p += (bytes + 255) & ~(size_t)255;
        return r;
    };
    int*      offs        = (int*)alloc((size_t)(N + 1) * 4);
    int*      bucketCount = (int*)alloc(256 * 4);
    float*    zbias       = (float*)alloc(64 * 4);        // zeroed with bucketCount
    int*      blockHist   = (int*)alloc(256 * CBPAD * 4);
    unsigned* ebuf        = (unsigned*)alloc((size_t)nbuck * CB * ECAP * 4);
    int*      csr         = (int*)alloc((size_t)E * 4);
    __bf16*   hbf         = (__bf16*)alloc((size_t)N * 64 * 2);  // h1, then y
    __bf16*   habg        = (__bf16*)alloc((size_t)N * 64 * 2);  // x2 = agg1 out
    float*    as_         = (float*)alloc((size_t)N * 4);
    float*    ad_         = (float*)alloc((size_t)N * 4);
    float*    as2_        = (float*)alloc((size_t)N * 4);
    float*    ad2_        = (float*)alloc((size_t)N * 4);
    float*    Wc          = (float*)alloc(64 * 40 * 4);
    float*    bc          = (float*)alloc(40 * 4);
    float*    u2          = (float*)alloc(64 * 4);
    float*    v2          = (float*)alloc(64 * 4);

    // bucketCount (1024B) and zbias (256B) are adjacent -> one memset
    hipMemsetAsync(bucketCount, 0, 1024 + 256, stream);

    const int nTiles = (N + 63) / 64;
    int aggBlocks = (N * 64 + 255) / 256;

    fused_hist_gemm<<<CB + 1 + nTiles, 256, 0, stream>>>(
        src, dst, bucketCount, blockHist, ebuf, E, CB,
        x, W1, a_src1, a_dst1, hbf, as_, ad_, N, nTiles,
        W2, Wl, bl, b2, a_src2, a_dst2, Wc, bc, u2, v2);
    bucket_fill<<<nbuck, 1024, 0, stream>>>(ebuf, blockHist, bucketCount,
                                            offs, csr, N, E, CB);
    gat_agg<<<aggBlocks, 256, 0, stream>>>(hbf, as_, ad_, b1, offs, csr, habg,
                                           N, 1, u2, v2, as2_, ad2_);
    gat_agg<<<aggBlocks, 256, 0, stream>>>(habg, as2_, ad2_, zbias, offs, csr, hbf,
                                           N, 0, nullptr, nullptr, nullptr, nullptr);
    final_lsm<<<512, 256, 0, stream>>>(hbf, Wc, bc, (float*)d_out, N, nTiles);
}